// Round 13
// baseline (1147.204 us; speedup 1.0000x reference)
//
#include <hip/hip_runtime.h>
#include <math.h>

// EfficientMemorySiLU: silu + exact 0.99-quantile + faithful f64 replication of
// jax's randomized SVD (CholeskyQR power iteration + bdsqr small SVD).
// R12 -> R13 (bit-identical launch-count reduction: 31 -> 21 dispatches):
//  - applyRinv folded into consumers: gemmA / gemmAT apply Uinv during LDS
//    staging (same ascending-k f64 sum -> round f32 == the value applyRinv
//    stored). Each Uinv consumed exactly once before being overwritten.
//  - reduceT folded into gram kernels: k_gramTR (T stages) / k_gramBR (B stage)
//    do chunk-ascending reduce -> f32 round -> write T/B -> gram in the old
//    kernels' exact tile order -> last-block redchol.

#define N_TOTAL 33554432
#define DDIM    4096
#define NROWS   8192
#define NCHUNK  32
#define RTARGET 33218888u   // f32(0.99)*f32(33554431) == 33218888.0 exactly

// ---------------- fast f64 helpers ----------------
__device__ __forceinline__ double frcp(double x){
  double r = (double)(1.0f/(float)x);
  r = r*(2.0 - x*r);
  r = r*(2.0 - x*r);
  return r;
}
__device__ __forceinline__ double frsqrt(double x){
  double r = (double)rsqrtf((float)x);
  double hx = 0.5*x;
  r = r*(1.5 - hx*r*r);
  r = r*(1.5 - hx*r*r);
  return r;
}
__device__ __forceinline__ double fsqrt(double x){
  return (x == 0.0) ? 0.0 : x*frsqrt(x);
}
__device__ __forceinline__ double frcp1(double x){
  double r = (double)(1.0f/(float)x);
  r = r*(2.0 - x*r);
  return r;
}
__device__ __forceinline__ double frsqrt1(double x){
  double r = (double)rsqrtf((float)x);
  r = r*(1.5 - (0.5*x)*r*r);
  return r;
}
__device__ __forceinline__ double fsqrt1(double x){
  return (x == 0.0) ? 0.0 : x*frsqrt1(x);
}

__device__ __forceinline__ double dsign(double a, double b){ return (b >= 0.0) ? fabs(a) : -fabs(a); }

__device__ __forceinline__ void f_slartg(double f, double g, double& c, double& s, double& r){
  if (g == 0.0){ c=1.0; s=0.0; r=f; }
  else if (f == 0.0){ c=0.0; s=dsign(1.0,g); r=fabs(g); }
  else {
    double d2 = f*f+g*g;
    double inv = frsqrt1(d2);
    c = fabs(f)*inv;
    r = dsign(d2*inv, f);
    s = g*inv*dsign(1.0,f);
  }
}

__device__ void f_slas2(double f, double g, double h, double& ssmin, double& ssmax){
  double fa=fabs(f), ga=fabs(g), ha=fabs(h);
  double fhmn=fmin(fa,ha), fhmx=fmax(fa,ha);
  if (fhmn == 0.0){
    ssmin=0.0;
    if (fhmx==0.0) ssmax=ga;
    else { double mx=fmax(fhmx,ga), mn=fmin(fhmx,ga); double q=mn*frcp1(mx); ssmax = mx*fsqrt1(1.0+q*q); }
  } else {
    if (ga < fhmx){
      double rinv = frcp1(fhmx);
      double as_=1.0+fhmn*rinv, at=(fhmx-fhmn)*rinv, au=ga*rinv; au=au*au;
      double c=2.0*frcp1(fsqrt1(as_*as_+au)+fsqrt1(at*at+au));
      ssmin=fhmn*c; ssmax=fhmx*frcp1(c);
    } else {
      double au=fhmx*frcp1(ga);
      if (au==0.0){ ssmin=(fhmn*fhmx)*frcp1(ga); ssmax=ga; }
      else {
        double rinv = frcp1(fhmx);
        double as_=1.0+fhmn*rinv, at=(fhmx-fhmn)*rinv;
        double c=frcp1(fsqrt1(1.0+(as_*au)*(as_*au))+fsqrt1(1.0+(at*au)*(at*au)));
        ssmin=(fhmn*c)*au; ssmin=ssmin+ssmin; ssmax=ga*frcp1(c+c);
      }
    }
  }
}

__device__ void f_slasv2(double f, double g, double h,
                         double& ssmin, double& ssmax, double& snr, double& csr, double& snl, double& csl){
  const double EPSd = 5.9604645e-8;
  double ft=f, fa=fabs(f), ht=h, ha=fabs(h);
  int pmax=1;
  bool swap_=(ha>fa);
  if (swap_){ pmax=3; double t=ft; ft=ht; ht=t; t=fa; fa=ha; ha=t; }
  double gt=g, ga=fabs(g);
  double clt=0, crt=0, slt=0, srt=0;
  if (ga == 0.0){ ssmin=ha; ssmax=fa; clt=1; crt=1; slt=0; srt=0; }
  else {
    bool gasmal=true;
    if (ga > fa){
      pmax=2;
      if ((fa*frcp1(ga)) < EPSd){
        gasmal=false;
        ssmax=ga;
        ssmin = (ha>1.0) ? (fa*frcp1(ga*frcp1(ha))) : ((fa*frcp1(ga))*ha);
        clt=1; slt=ht*frcp1(gt); srt=1; crt=ft*frcp1(gt);
      }
    }
    if (gasmal){
      double d_=fa-ha;
      double fainv = frcp1(fa);
      double l_=(d_==fa)?1.0:(d_*fainv);
      double m_=gt*frcp1(ft);
      double t_=2.0-l_;
      double mm=m_*m_, tt=t_*t_;
      double s_=fsqrt1(tt+mm);
      double r_=(l_==0.0)?fabs(m_):fsqrt1(l_*l_+mm);
      double a_=0.5*(s_+r_);
      double ainv = frcp1(a_);
      ssmin=ha*ainv;
      ssmax=fa*a_;
      if (mm==0.0){
        t_=(l_==0.0)?(dsign(2.0,ft)*dsign(1.0,gt)):(gt*frcp1(dsign(d_,ft))+m_*frcp1(t_));
      } else {
        t_=(m_*frcp1(s_+t_)+m_*frcp1(r_+l_))*(1.0+a_);
      }
      l_=fsqrt1(t_*t_+4.0);
      double linv = frcp1(l_);
      crt=2.0*linv;
      srt=t_*linv;
      clt=(crt+srt*m_)*ainv;
      slt=(ht*frcp1(ft))*srt*ainv;
    }
  }
  if (swap_){ csl=srt; snl=crt; csr=slt; snr=clt; }
  else { csl=clt; snl=slt; csr=crt; snr=srt; }
  double tsign=0.0;
  if (pmax==1) tsign = dsign(1.0,csr)*dsign(1.0,csl)*dsign(1.0,f);
  if (pmax==2) tsign = dsign(1.0,snr)*dsign(1.0,csl)*dsign(1.0,g);
  if (pmax==3) tsign = dsign(1.0,snr)*dsign(1.0,snl)*dsign(1.0,h);
  ssmax = dsign(ssmax, tsign);
  ssmin = dsign(ssmin, tsign*dsign(1.0,f)*dsign(1.0,h));
}

// ---------------- histogram / selection ----------------
__global__ __launch_bounds__(256) void k_hist1(const float4* __restrict__ x4, unsigned* __restrict__ h1){
  __shared__ unsigned lh[4096];
  for (int i=threadIdx.x; i<4096; i+=256) lh[i]=0u;
  __syncthreads();
  int tid = blockIdx.x*blockDim.x + threadIdx.x;
  int stride = gridDim.x*blockDim.x;
  for (int i = tid; i < N_TOTAL/4; i += stride){
    float4 v = x4[i];
    atomicAdd(&lh[(__float_as_uint(v.x)&0x7FFFFFFFu)>>19], 1u);
    atomicAdd(&lh[(__float_as_uint(v.y)&0x7FFFFFFFu)>>19], 1u);
    atomicAdd(&lh[(__float_as_uint(v.z)&0x7FFFFFFFu)>>19], 1u);
    atomicAdd(&lh[(__float_as_uint(v.w)&0x7FFFFFFFu)>>19], 1u);
  }
  __syncthreads();
  for (int i=threadIdx.x; i<4096; i+=256){ unsigned c=lh[i]; if (c) atomicAdd(&h1[i], c); }
}

__global__ __launch_bounds__(256) void k_siluhist(const float4* __restrict__ x4, float4* __restrict__ o4,
                                                  unsigned* __restrict__ h1){
  __shared__ unsigned lh[4096];
  for (int i=threadIdx.x; i<4096; i+=256) lh[i]=0u;
  __syncthreads();
  int tid = blockIdx.x*blockDim.x + threadIdx.x;
  int stride = gridDim.x*blockDim.x;
  for (int i = tid; i < N_TOTAL/4; i += stride){
    float4 v = x4[i];
    float4 o;
    o.x = v.x / (1.0f + expf(-v.x));
    o.y = v.y / (1.0f + expf(-v.y));
    o.z = v.z / (1.0f + expf(-v.z));
    o.w = v.w / (1.0f + expf(-v.w));
    o4[i] = o;
    atomicAdd(&lh[(__float_as_uint(v.x)&0x7FFFFFFFu)>>19], 1u);
    atomicAdd(&lh[(__float_as_uint(v.y)&0x7FFFFFFFu)>>19], 1u);
    atomicAdd(&lh[(__float_as_uint(v.z)&0x7FFFFFFFu)>>19], 1u);
    atomicAdd(&lh[(__float_as_uint(v.w)&0x7FFFFFFFu)>>19], 1u);
  }
  __syncthreads();
  for (int i=threadIdx.x; i<4096; i+=256){ unsigned c=lh[i]; if (c) atomicAdd(&h1[i], c); }
}

__global__ __launch_bounds__(1024) void k_select1(const unsigned* __restrict__ h1, unsigned* __restrict__ sel){
  __shared__ unsigned ssum[1024];
  int t = threadIdx.x;
  unsigned psum = 0;
  for (int k=0;k<4;++k) psum += h1[t*4+k];
  ssum[t]=psum; __syncthreads();
  for (int off=1; off<1024; off<<=1){
    unsigned v = (t>=off)? ssum[t-off]:0u;
    __syncthreads();
    ssum[t] += v;
    __syncthreads();
  }
  unsigned incl = ssum[t], excl = incl - psum;
  if (excl <= RTARGET && RTARGET < incl){
    unsigned run = excl;
    for (int k=0;k<4;++k){
      unsigned c = h1[t*4+k];
      if (run + c > RTARGET){ sel[1]=(unsigned)(t*4+k); sel[2]=RTARGET-run; break; }
      run += c;
    }
  }
}

__global__ void k_hist2(const float4* __restrict__ x4, unsigned* __restrict__ h2, const unsigned* __restrict__ sel){
  unsigned hstar = sel[1];
  int tid = blockIdx.x*blockDim.x + threadIdx.x;
  int stride = gridDim.x*blockDim.x;
  for (int i = tid; i < N_TOTAL/4; i += stride){
    float4 v = x4[i];
    unsigned b;
    b = __float_as_uint(v.x) & 0x7FFFFFFFu; if ((b>>19)==hstar) atomicAdd(&h2[b&0x7FFFFu],1u);
    b = __float_as_uint(v.y) & 0x7FFFFFFFu; if ((b>>19)==hstar) atomicAdd(&h2[b&0x7FFFFu],1u);
    b = __float_as_uint(v.z) & 0x7FFFFFFFu; if ((b>>19)==hstar) atomicAdd(&h2[b&0x7FFFFu],1u);
    b = __float_as_uint(v.w) & 0x7FFFFFFFu; if ((b>>19)==hstar) atomicAdd(&h2[b&0x7FFFFu],1u);
  }
}

__global__ __launch_bounds__(128) void k_grpsum(const uint4* __restrict__ h2v, unsigned* __restrict__ gs){
  __shared__ unsigned red[128];
  int g = blockIdx.x, t = threadIdx.x;
  uint4 v = h2v[(size_t)g*128 + t];
  red[t] = v.x+v.y+v.z+v.w;
  __syncthreads();
  for (int off=64; off; off>>=1){ if (t<off) red[t] += red[t+off]; __syncthreads(); }
  if (t==0) gs[g] = red[0];
}

__global__ __launch_bounds__(1024) void k_select2b(const unsigned* __restrict__ gs, const unsigned* __restrict__ h2,
                                                   unsigned* __restrict__ sel, float* __restrict__ outScalar){
  __shared__ unsigned ssum[1024];
  __shared__ unsigned sg[2];
  int t = threadIdx.x;
  unsigned target = sel[2], hstar = sel[1];
  unsigned psum = gs[t];
  ssum[t]=psum; __syncthreads();
  for (int off=1; off<1024; off<<=1){
    unsigned v = (t>=off)? ssum[t-off]:0u;
    __syncthreads();
    ssum[t] += v;
    __syncthreads();
  }
  unsigned incl = ssum[t], excl = incl - psum;
  if (excl <= target && target < incl){ sg[0]=(unsigned)t; sg[1]=excl; }
  __syncthreads();
  unsigned g = sg[0], gexcl = sg[1];
  unsigned cnt = (t<512) ? h2[(size_t)g*512 + t] : 0u;
  __syncthreads();
  ssum[t]=cnt; __syncthreads();
  for (int off=1; off<1024; off<<=1){
    unsigned v = (t>=off)? ssum[t-off]:0u;
    __syncthreads();
    ssum[t] += v;
    __syncthreads();
  }
  unsigned incl2 = ssum[t], excl2 = incl2 - cnt;
  unsigned rem = target - gexcl;
  if (t < 512 && excl2 <= rem && rem < incl2){
    unsigned tb = (hstar<<19) | (g*512 + (unsigned)t);
    float tv = __uint_as_float(tb);
    ((float*)sel)[0] = tv;
    *outScalar = tv;
  }
}

// ---------------- Omega: exact jax.random.normal(key(42),(4096,16)) ----------------
__device__ __forceinline__ unsigned rotl32(unsigned x, int r){ return (x<<r)|(x>>(32-r)); }

__device__ __forceinline__ float bits_to_normal(unsigned g){
  float u01 = __uint_as_float((g>>9) | 0x3F800000u) - 1.0f;
  float u = __fadd_rn(__fmul_rn(u01, 2.0f), -0.99999994f);
  u = fmaxf(-0.99999994f, u);
  float xx = __fmul_rn(u,u);
  float w = -log1pf(-xx);
  float p;
  if (w < 5.0f){
    w = __fadd_rn(w, -2.5f);
    p = 2.81022636e-08f;
    p = __fadd_rn(3.43273939e-07f, __fmul_rn(p,w));
    p = __fadd_rn(-3.5233877e-06f, __fmul_rn(p,w));
    p = __fadd_rn(-4.39150654e-06f, __fmul_rn(p,w));
    p = __fadd_rn(0.00021858087f, __fmul_rn(p,w));
    p = __fadd_rn(-0.00125372503f, __fmul_rn(p,w));
    p = __fadd_rn(-0.00417768164f, __fmul_rn(p,w));
    p = __fadd_rn(0.246640727f, __fmul_rn(p,w));
    p = __fadd_rn(1.50140941f, __fmul_rn(p,w));
  } else {
    w = __fadd_rn(sqrtf(w), -3.0f);
    p = -0.000200214257f;
    p = __fadd_rn(0.000100950558f, __fmul_rn(p,w));
    p = __fadd_rn(0.00134934322f, __fmul_rn(p,w));
    p = __fadd_rn(-0.00367342844f, __fmul_rn(p,w));
    p = __fadd_rn(0.00573950773f, __fmul_rn(p,w));
    p = __fadd_rn(-0.0076224613f, __fmul_rn(p,w));
    p = __fadd_rn(0.00943887047f, __fmul_rn(p,w));
    p = __fadd_rn(1.00167406f, __fmul_rn(p,w));
    p = __fadd_rn(2.83297682f, __fmul_rn(p,w));
  }
  return __fmul_rn(__uint_as_float(0x3FB504F3u), __fmul_rn(p,u));
}

#define TF_ROUND(r) { x0 += x1; x1 = rotl32(x1,(r)); x1 ^= x0; }

__global__ void k_omega(float* __restrict__ om){
  unsigned p = blockIdx.x*blockDim.x + threadIdx.x;
  unsigned x0 = p, x1 = 32768u + p;
  const unsigned ks0 = 0u, ks1 = 42u, ks2 = 0x1BD11BDAu ^ 0u ^ 42u;
  x0 += ks0; x1 += ks1;
  TF_ROUND(13) TF_ROUND(15) TF_ROUND(26) TF_ROUND(6)   x0+=ks1; x1+=ks2+1u;
  TF_ROUND(17) TF_ROUND(29) TF_ROUND(16) TF_ROUND(24)  x0+=ks2; x1+=ks0+2u;
  TF_ROUND(13) TF_ROUND(15) TF_ROUND(26) TF_ROUND(6)   x0+=ks0; x1+=ks1+3u;
  TF_ROUND(17) TF_ROUND(29) TF_ROUND(16) TF_ROUND(24)  x0+=ks1; x1+=ks2+4u;
  TF_ROUND(13) TF_ROUND(15) TF_ROUND(26) TF_ROUND(6)   x0+=ks2; x1+=ks0+5u;
  om[p]         = bits_to_normal(x0);
  om[p+32768u]  = bits_to_normal(x1);
}

// ---------------- GEMMs (f64 accumulation; f32 LDS staging; optional Uinv fold) ----------------
// Y[8192][16] = Xs @ (applyU ? W*Uinv : W)
__global__ __launch_bounds__(256) void k_gemmA(const float* __restrict__ x, const float* __restrict__ W,
                                               float* __restrict__ Y, const float* __restrict__ sel,
                                               const double* __restrict__ UinvG, int applyU){
  __shared__ float xs[16][128];
  __shared__ float ws[128][16];
  __shared__ double su[256];
  const float t = sel[0];
  const int tid = threadIdx.x;
  const int c = tid & 15, rl = tid >> 4;
  const int row0 = blockIdx.x*16;
  const int c8 = c*8;
  const int wk = (tid*8) >> 4, wc = (tid*8) & 15;
  if (applyU) su[tid] = UinvG[tid];
  __syncthreads();
  double acc = 0.0;
  for (int kt = 0; kt < DDIM; kt += 128){
    const float4* p = (const float4*)(x + (size_t)(row0+rl)*DDIM + kt + c8);
    float4 a = p[0], b = p[1];
    xs[rl][c8+0] = (fabsf(a.x) > t) ? 0.0f : a.x;
    xs[rl][c8+1] = (fabsf(a.y) > t) ? 0.0f : a.y;
    xs[rl][c8+2] = (fabsf(a.z) > t) ? 0.0f : a.z;
    xs[rl][c8+3] = (fabsf(a.w) > t) ? 0.0f : a.w;
    xs[rl][c8+4] = (fabsf(b.x) > t) ? 0.0f : b.x;
    xs[rl][c8+5] = (fabsf(b.y) > t) ? 0.0f : b.y;
    xs[rl][c8+6] = (fabsf(b.z) > t) ? 0.0f : b.z;
    xs[rl][c8+7] = (fabsf(b.w) > t) ? 0.0f : b.w;
    if (applyU){
      const float* trow = W + (size_t)(kt+wk)*16;
      const float4* t4 = (const float4*)trow;
      float4 ta=t4[0], tb=t4[1], tc=t4[2], td=t4[3];
      float tv[16] = {ta.x,ta.y,ta.z,ta.w, tb.x,tb.y,tb.z,tb.w,
                      tc.x,tc.y,tc.z,tc.w, td.x,td.y,td.z,td.w};
      #pragma unroll
      for (int jj=0;jj<8;++jj){
        double s2 = 0.0;
        #pragma unroll
        for (int k2=0;k2<16;++k2) s2 += (double)tv[k2]*su[k2*16 + wc+jj];
        ws[wk][wc+jj] = (float)s2;
      }
    } else {
      const float4* q = (const float4*)(W + (size_t)kt*16 + tid*8);
      float4 wa = q[0], wb = q[1];
      float* dstw = &ws[wk][wc];
      dstw[0]=wa.x; dstw[1]=wa.y; dstw[2]=wa.z; dstw[3]=wa.w;
      dstw[4]=wb.x; dstw[5]=wb.y; dstw[6]=wb.z; dstw[7]=wb.w;
    }
    __syncthreads();
    #pragma unroll
    for (int k=0;k<128;k+=2){
      float2 xv2 = *(const float2*)&xs[rl][k];
      acc += (double)xv2.x*(double)ws[k][c];
      acc += (double)xv2.y*(double)ws[k+1][c];
    }
    __syncthreads();
  }
  Y[(size_t)(row0+rl)*16 + c] = (float)acc;
}

// part[chunk][4096][16] = Xs^T @ (Yraw*Uinv)
__global__ __launch_bounds__(256) void k_gemmAT(const float* __restrict__ x, const float* __restrict__ Q,
                                                const double* __restrict__ UinvG,
                                                double* __restrict__ part, const float* __restrict__ sel){
  __shared__ float qs[128][16];
  __shared__ double su[256];
  const float t = sel[0];
  const int tid = threadIdx.x;
  const int d = blockIdx.x*256 + tid;
  const int chunk = blockIdx.y;
  const int i0 = chunk*(NROWS/NCHUNK);
  su[tid] = UinvG[tid];
  __syncthreads();
  double acc[16];
  #pragma unroll
  for (int c=0;c<16;++c) acc[c]=0.0;
  for (int it=0; it<NROWS/NCHUNK; it+=128){
    if (tid < 128){
      const float4* src = (const float4*)(Q + (size_t)(i0+it+tid)*16);
      float4 a = src[0], b = src[1], c4 = src[2], d4 = src[3];
      float yv[16] = {a.x,a.y,a.z,a.w, b.x,b.y,b.z,b.w,
                      c4.x,c4.y,c4.z,c4.w, d4.x,d4.y,d4.z,d4.w};
      #pragma unroll
      for (int jj=0;jj<16;++jj){
        double s2 = 0.0;
        #pragma unroll
        for (int k2=0;k2<16;++k2) s2 += (double)yv[k2]*su[k2*16 + jj];
        qs[tid][jj] = (float)s2;
      }
    }
    __syncthreads();
    for (int ii=0; ii<128; ++ii){
      float xv = x[(size_t)(i0+it+ii)*DDIM + d];
      xv = (fabsf(xv) > t) ? 0.0f : xv;
      double xd = (double)xv;
      #pragma unroll
      for (int c2=0;c2<8;++c2){
        float2 q2 = *(const float2*)&qs[ii][c2*2];
        acc[c2*2]   += xd*(double)q2.x;
        acc[c2*2+1] += xd*(double)q2.y;
      }
    }
    __syncthreads();
  }
  double* pp = part + ((size_t)chunk*DDIM + d)*16;
  #pragma unroll
  for (int c=0;c<16;++c) pp[c]=acc[c];
}

// ---------------- CholeskyQR building blocks ----------------
__device__ void redchol_body(const double* part, int nchunks, double* Lout, double* Uinv,
                             double (*Gs)[17], double (*Vs)[17], int t){
  {
    double s = 0.0;
    for (int c=0;c<nchunks;++c) s += part[(size_t)c*256 + t];
    Gs[t>>4][t&15] = s;
  }
  __syncthreads();
  int l = t;
  for (int k=0;k<16;++k){
    if (l==k) Gs[k][k] = fsqrt(Gs[k][k]);
    __syncthreads();
    if (l>k && l<16) Gs[k][l] = Gs[k][l]*frcp(Gs[k][k]);
    __syncthreads();
    if (l>k && l<16){
      double g = Gs[k][l];
      for (int i=k+1;i<=l;++i) Gs[i][l] -= Gs[k][i]*g;
    }
    __syncthreads();
  }
  if (l<16){
    for (int i=0;i<16;++i) Vs[i][l] = 0.0;
    Vs[l][l] = frcp(Gs[l][l]);
    for (int i=l-1;i>=0;--i){
      double s = 0.0;
      for (int k=i+1;k<=l;++k) s += Gs[i][k]*Vs[k][l];
      Vs[i][l] = -s*frcp(Gs[i][i]);
    }
  }
  __syncthreads();
  if (l<16){
    for (int c=0;c<16;++c){
      Lout[l*16+c] = (c<=l) ? Gs[c][l] : 0.0;
      Uinv[l*16+c] = (l<=c) ? Vs[l][c] : 0.0;
    }
  }
}

// gram of M (N x 16, already in f32 global) with fused last-block redchol
__global__ __launch_bounds__(256) void k_gramMC(const float* __restrict__ M, int rowsPerChunk,
                                                double* __restrict__ part,
                                                double* __restrict__ Lout, double* __restrict__ Uinv,
                                                unsigned* __restrict__ ctr){
  __shared__ float lds[16][17];
  __shared__ double Gs[16][17];
  __shared__ double Vs[16][17];
  __shared__ unsigned slast;
  int t = threadIdx.x; int i = t>>4, j = t&15;
  int r0 = blockIdx.x*rowsPerChunk;
  double acc = 0.0;
  for (int rt=0; rt<rowsPerChunk; rt+=16){
    lds[t>>4][t&15] = M[(size_t)(r0+rt+(t>>4))*16 + (t&15)];
    __syncthreads();
    #pragma unroll
    for (int dd2=0; dd2<16; ++dd2) acc += (double)lds[dd2][i]*(double)lds[dd2][j];
    __syncthreads();
  }
  part[(size_t)blockIdx.x*256 + t] = acc;
  __threadfence();
  if (t==0) slast = atomicAdd(ctr, 1u);
  __syncthreads();
  if (slast != gridDim.x-1u) return;
  __threadfence();
  redchol_body(part, (int)gridDim.x, Lout, Uinv, Gs, Vs, t);
  __syncthreads();
  if (t==0) *ctr = 0u;
}

// fused: reduce partials -> T (f32, written) -> gram (gramMC order) -> last-block redchol
__global__ __launch_bounds__(256) void k_gramTR(const double* __restrict__ part, float* __restrict__ T,
                                                double* __restrict__ partG,
                                                double* __restrict__ Lout, double* __restrict__ Uinv,
                                                unsigned* __restrict__ ctr){
  __shared__ float sT[128][17];
  __shared__ double Gs[16][17];
  __shared__ double Vs[16][17];
  __shared__ unsigned slast;
  int t = threadIdx.x; int i = t>>4, j = t&15;
  int b = blockIdx.x;   // 32 blocks x 128 rows
  #pragma unroll
  for (int e=0;e<8;++e){
    int idx = t + e*256;
    int row = idx >> 4, col = idx & 15;
    size_t gidx = ((size_t)(b*128 + row))*16 + col;
    double s = 0.0;
    for (int c=0;c<NCHUNK;++c) s += part[(size_t)c*DDIM*16 + gidx];
    float v = (float)s;
    sT[row][col] = v;
    T[gidx] = v;
  }
  __syncthreads();
  double acc = 0.0;
  for (int rt=0; rt<128; rt+=16){
    #pragma unroll
    for (int dd2=0; dd2<16; ++dd2) acc += (double)sT[rt+dd2][i]*(double)sT[rt+dd2][j];
  }
  partG[(size_t)b*256 + t] = acc;
  __threadfence();
  if (t==0) slast = atomicAdd(ctr, 1u);
  __syncthreads();
  if (slast != gridDim.x-1u) return;
  __threadfence();
  redchol_body(partG, (int)gridDim.x, Lout, Uinv, Gs, Vs, t);
  __syncthreads();
  if (t==0) *ctr = 0u;
}

// fused: reduce partials -> B (f32, written) -> gram over columns (gramBC order) -> redchol
__global__ __launch_bounds__(256) void k_gramBR(const double* __restrict__ part, float* __restrict__ B,
                                                double* __restrict__ partG,
                                                double* __restrict__ Lout, double* __restrict__ Uinv,
                                                unsigned* __restrict__ ctr){
  __shared__ float sB[16][257];
  __shared__ double Gs[16][17];
  __shared__ double Vs[16][17];
  __shared__ unsigned slast;
  int t = threadIdx.x; int i = t>>4, j = t&15;
  int b = blockIdx.x; int d0 = b*256;   // 16 blocks x 256 cols
  #pragma unroll
  for (int e=0;e<16;++e){
    int idx = t + e*256;
    int r = idx >> 8;
    int dl = idx & 255;
    size_t gidx = ((size_t)(d0+dl))*16 + r;
    double s = 0.0;
    for (int c=0;c<NCHUNK;++c) s += part[(size_t)c*DDIM*16 + gidx];
    float v = (float)s;
    sB[r][dl] = v;
    B[(size_t)r*DDIM + d0+dl] = v;
  }
  __syncthreads();
  double acc = 0.0;
  for (int dt=0; dt<256; dt+=16){
    #pragma unroll
    for (int dd2=0; dd2<16; ++dd2) acc += (double)sB[i][dt+dd2]*(double)sB[j][dt+dd2];
  }
  partG[(size_t)b*256 + t] = acc;
  __threadfence();
  if (t==0) slast = atomicAdd(ctr, 1u);
  __syncthreads();
  if (slast != gridDim.x-1u) return;
  __threadfence();
  redchol_body(partG, (int)gridDim.x, Lout, Uinv, Gs, Vs, t);
  __syncthreads();
  if (t==0) *ctr = 0u;
}

// ---------------- small SVD core (R8/R11 structure) ----------------
__global__ __launch_bounds__(64) void k_smallsvd(const double* __restrict__ Lg, double* __restrict__ Wout){
  __shared__ double Lm[16][16];
  __shared__ double VT[16][16];
  __shared__ double A1[16][16];
  __shared__ double dd[16], ee[16], tp[16];
  __shared__ double csv[16], snv[16];
  int l = threadIdx.x;
  for (int idx=l; idx<256; idx+=64){ int r=idx>>4, c=idx&15; Lm[r][c] = (c<=r)? Lg[r*16+c] : 0.0; }
  __syncthreads();
  for (int i=0;i<16;++i){
    double xn2=0.0;
    for (int r=i+1;r<16;++r){ double v=Lm[r][i]; xn2 += v*v; }
    double alpha = Lm[i][i];
    double beta, tauq_, scl;
    if (xn2==0.0){ tauq_=0.0; beta=alpha; scl=0.0; }
    else { beta = -dsign(fsqrt1(alpha*alpha+xn2), alpha); tauq_=(beta-alpha)*frcp1(beta); scl=frcp1(alpha-beta); }
    __syncthreads();
    if (l>i && l<16) Lm[l][i] *= scl;
    __syncthreads();
    dd[i]=beta;
    if (tauq_ != 0.0 && l>i && l<16){
      int j=l;
      double w = Lm[i][j];
      for (int r=i+1;r<16;++r) w += Lm[r][i]*Lm[r][j];
      w *= tauq_;
      Lm[i][j] -= w;
      for (int r=i+1;r<16;++r) Lm[r][j] -= w*Lm[r][i];
    }
    __syncthreads();
    if (i<15){
      double xn2b=0.0;
      for (int c=i+2;c<16;++c){ double v=Lm[i][c]; xn2b+=v*v; }
      double alpha2=Lm[i][i+1];
      double beta2, taup_, scl2;
      if (xn2b==0.0){ taup_=0.0; beta2=alpha2; scl2=0.0; }
      else { beta2=-dsign(fsqrt1(alpha2*alpha2+xn2b),alpha2); taup_=(beta2-alpha2)*frcp1(beta2); scl2=frcp1(alpha2-beta2); }
      __syncthreads();
      if (l>=i+2 && l<16) Lm[i][l] *= scl2;
      __syncthreads();
      ee[i]=beta2; tp[i]=taup_;
      if (taup_!=0.0 && l>i && l<16){
        int r=l;
        double w=Lm[r][i+1];
        for (int c=i+2;c<16;++c) w += Lm[i][c]*Lm[r][c];
        w *= taup_;
        Lm[r][i+1] -= w;
        for (int c=i+2;c<16;++c) Lm[r][c] -= w*Lm[i][c];
      }
      __syncthreads();
    } else { tp[i]=0.0; __syncthreads(); }
  }
  for (int idx=l; idx<256; idx+=64){ int r=idx>>4,c=idx&15; VT[r][c]=(r==c)?1.0:0.0; }
  __syncthreads();
  const double EPSs = 5.9604645e-8;
  const double UNFL = 1.17549435e-38;
  double tol = 10.0*EPSs;
  double sminoa, mu;
  sminoa = mu = fabs(dd[0]);
  if (sminoa != 0.0){
    for (int k=1;k<16;++k){ mu = fabs(dd[k])*(mu*frcp1(mu+fabs(ee[k-1]))); sminoa=fmin(sminoa,mu); if (sminoa==0.0) break; }
  }
  sminoa = sminoa/4.0;
  double thresh = fmax(tol*sminoa, 6.0*16.0*16.0*UNFL);
  int m=16, oldll=-1, oldm=-1, idir=0;
  double sminl=0.0;
  int guard=0;
  #define Dv(k) dd[(k)-1]
  #define Ev(k) ee[(k)-1]
  while (m > 1 && guard < 3000){
    ++guard;
    int ll=0; bool split=false;
    double smax_=fabs(Dv(m)), smin_=smax_;
    for (int lll=1; lll<=m-1; ++lll){
      ll = m-lll;
      double abss=fabs(Dv(ll)), abse=fabs(Ev(ll));
      if (abse <= thresh){ split=true; break; }
      smin_=fmin(smin_,abss); smax_=fmax(smax_,fmax(abss,abse));
    }
    if (!split) ll=0;
    else {
      Ev(ll)=0.0;
      if (ll == m-1){ m = m-1; continue; }
    }
    ll = ll+1;
    if (ll == m-1){
      double sigmn,sigmx,sinr,cosr,sinl_,cosl;
      f_slasv2(Dv(m-1), Ev(m-1), Dv(m), sigmn, sigmx, sinr, cosr, sinl_, cosl);
      Dv(m-1)=sigmx; Ev(m-1)=0.0; Dv(m)=sigmn;
      if (l<16){
        double t0 = cosr*VT[m-2][l] + sinr*VT[m-1][l];
        VT[m-1][l] = cosr*VT[m-1][l] - sinr*VT[m-2][l];
        VT[m-2][l] = t0;
      }
      __syncthreads();
      m -= 2; continue;
    }
    if (ll > oldm || m < oldll) idir = (fabs(Dv(ll)) >= fabs(Dv(m))) ? 1 : 2;
    bool cont=false;
    if (idir==1){
      if (fabs(Ev(m-1)) <= tol*fabs(Dv(m))){ Ev(m-1)=0.0; continue; }
      mu = fabs(Dv(ll)); sminl=mu;
      for (int lll=ll; lll<=m-1; ++lll){
        if (fabs(Ev(lll)) <= tol*mu){ Ev(lll)=0.0; cont=true; break; }
        mu = fabs(Dv(lll+1))*(mu*frcp1(mu+fabs(Ev(lll)))); sminl=fmin(sminl,mu);
      }
    } else {
      if (fabs(Ev(ll)) <= tol*fabs(Dv(ll))){ Ev(ll)=0.0; continue; }
      mu = fabs(Dv(m)); sminl=mu;
      for (int lll=m-1; lll>=ll; --lll){
        if (fabs(Ev(lll)) <= tol*mu){ Ev(lll)=0.0; cont=true; break; }
        mu = fabs(Dv(lll))*(mu*frcp1(mu+fabs(Ev(lll)))); sminl=fmin(sminl,mu);
      }
    }
    if (cont) continue;
    oldll=ll; oldm=m;
    double shift=0.0, rdum;
    if (!( 16.0*tol*(sminl*frcp1(smax_)) <= fmax(EPSs, 0.01*tol) )){
      double sll;
      if (idir==1){ sll=fabs(Dv(ll)); f_slas2(Dv(m-1), Ev(m-1), Dv(m), shift, rdum); }
      else        { sll=fabs(Dv(m));  f_slas2(Dv(ll), Ev(ll), Dv(ll+1), shift, rdum); }
      if (sll>0.0){ double q=shift*frcp1(sll); if (q*q < EPSs) shift=0.0; }
    }
    if (shift == 0.0){
      if (idir==1){
        double cs=1.0, oldcs=1.0, oldsn=0.0, r_;
        double dcur = Dv(ll);
        for (int i1=ll;i1<=m-1;++i1){
          double cn, snn;
          double a0 = dcur*cs;
          f_slartg(a0, Ev(i1), cn, snn, r_);
          if (i1>ll) Ev(i1-1) = oldsn*r_;
          double dnx = Dv(i1+1);
          double ocn, osn, dnew;
          f_slartg(oldcs*r_, dnx*snn, ocn, osn, dnew);
          Dv(i1)=dnew;
          cs=cn; oldcs=ocn; oldsn=osn;
          csv[i1-1]=cs; snv[i1-1]=snn;
          dcur = dnx;
        }
        double h=dcur*cs;
        Dv(m)=h*oldcs; Ev(m-1)=h*oldsn;
        if (fabs(Ev(m-1))<=thresh) Ev(m-1)=0.0;
        __syncthreads();
        if (l<16){
          double v = VT[ll-1][l];
          for (int i1=ll;i1<=m-1;++i1){
            double c=csv[i1-1], s=snv[i1-1];
            double w = VT[i1][l];
            VT[i1-1][l] = c*v + s*w;
            v = c*w - s*v;
          }
          VT[m-1][l] = v;
        }
      } else {
        double cs=1.0, oldcs=1.0, oldsn=0.0, r_;
        double dcur = Dv(m);
        for (int i1=m;i1>=ll+1;--i1){
          double cn,snn;
          double a0 = dcur*cs;
          f_slartg(a0, Ev(i1-1), cn, snn, r_);
          if (i1<m) Ev(i1)=oldsn*r_;
          double dnx = Dv(i1-1);
          double ocn,osn,dnew;
          f_slartg(oldcs*r_, dnx*snn, ocn, osn, dnew);
          Dv(i1)=dnew;
          cs=cn; oldcs=ocn; oldsn=osn;
          csv[i1-2]=oldcs; snv[i1-2]=-oldsn;
          dcur = dnx;
        }
        double h=dcur*cs;
        Dv(ll)=h*oldcs; Ev(ll)=h*oldsn;
        if (fabs(Ev(ll))<=thresh) Ev(ll)=0.0;
        __syncthreads();
        if (l<16){
          double v = VT[m-1][l];
          for (int i1=m;i1>=ll+1;--i1){
            double c=csv[i1-2], s=snv[i1-2];
            double w = VT[i1-2][l];
            VT[i1-1][l] = c*v - s*w;
            v = c*w + s*v;
          }
          VT[ll-1][l] = v;
        }
      }
    } else {
      if (idir==1){
        double f=(fabs(Dv(ll))-shift)*(dsign(1.0,Dv(ll))+shift*frcp1(Dv(ll)));
        double g=Ev(ll);
        double dcur = Dv(ll), ecur = Ev(ll);
        double r_;
        for (int i1=ll;i1<=m-1;++i1){
          double cosr,sinr,cosl,sinl_;
          double dnx = Dv(i1+1);
          f_slartg(f,g,cosr,sinr,r_);
          if (i1>ll) Ev(i1-1)=r_;
          f = cosr*dcur + sinr*ecur;
          double e_mid = cosr*ecur - sinr*dcur;
          g = sinr*dnx;
          double d_mid = cosr*dnx;
          f_slartg(f,g,cosl,sinl_,r_);
          Dv(i1)=r_;
          f = cosl*e_mid + sinl_*d_mid;
          double d_fin = cosl*d_mid - sinl_*e_mid;
          double e_fin = 0.0;
          if (i1 < m-1){ double enx = Ev(i1+1); g = sinl_*enx; e_fin = cosl*enx; }
          csv[i1-1]=cosr; snv[i1-1]=sinr;
          dcur = d_fin; ecur = e_fin;
        }
        Dv(m) = dcur;
        Ev(m-1)=f;
        if (fabs(Ev(m-1))<=thresh) Ev(m-1)=0.0;
        __syncthreads();
        if (l<16){
          double v = VT[ll-1][l];
          for (int i1=ll;i1<=m-1;++i1){
            double c=csv[i1-1], s=snv[i1-1];
            double w = VT[i1][l];
            VT[i1-1][l] = c*v + s*w;
            v = c*w - s*v;
          }
          VT[m-1][l] = v;
        }
      } else {
        double f=(fabs(Dv(m))-shift)*(dsign(1.0,Dv(m))+shift*frcp1(Dv(m)));
        double g=Ev(m-1);
        double dcur = Dv(m), ecur = Ev(m-1);
        double r_;
        for (int i1=m;i1>=ll+1;--i1){
          double cosr,sinr,cosl,sinl_;
          double dnx = Dv(i1-1);
          f_slartg(f,g,cosr,sinr,r_);
          if (i1<m) Ev(i1)=r_;
          f = cosr*dcur + sinr*ecur;
          double e_mid = cosr*ecur - sinr*dcur;
          g = sinr*dnx;
          double d_mid = cosr*dnx;
          f_slartg(f,g,cosl,sinl_,r_);
          Dv(i1)=r_;
          f = cosl*e_mid + sinl_*d_mid;
          double d_fin = cosl*d_mid - sinl_*e_mid;
          double e_fin = 0.0;
          if (i1 > ll+1){ double enx = Ev(i1-2); g = sinl_*enx; e_fin = cosl*enx; }
          csv[i1-2]=cosr; snv[i1-2]=-sinr;
          dcur = d_fin; ecur = e_fin;
        }
        Dv(ll) = dcur;
        Ev(ll)=f;
        if (fabs(Ev(ll))<=thresh) Ev(ll)=0.0;
        __syncthreads();
        if (l<16){
          double v = VT[m-1][l];
          for (int i1=m;i1>=ll+1;--i1){
            double c=csv[i1-2], s=snv[i1-2];
            double w = VT[i1-2][l];
            VT[i1-1][l] = c*v - s*w;
            v = c*w + s*v;
          }
          VT[ll-1][l] = v;
        }
      }
    }
    __syncthreads();
  }
  __syncthreads();
  for (int k=1;k<=16;++k){
    if (Dv(k) < 0.0){
      Dv(k) = -Dv(k);
      if (l<16) VT[k-1][l] = -VT[k-1][l];
    }
    __syncthreads();
  }
  for (int i1=1;i1<=15;++i1){
    int isub=1; double smn=Dv(1);
    for (int j=2;j<=17-i1;++j){ if (Dv(j) <= smn){ isub=j; smn=Dv(j);} }
    if (isub != 17-i1){
      double tmpd = Dv(17-i1);
      __syncthreads();
      Dv(isub)=tmpd; Dv(17-i1)=smn;
      if (l<16){ double t2=VT[isub-1][l]; VT[isub-1][l]=VT[16-i1][l]; VT[16-i1][l]=t2; }
    }
    __syncthreads();
  }
  for (int i=14;i>=0;--i){
    double tpv = tp[i];
    if (tpv != 0.0 && l<16){
      int r=l;
      double w = VT[r][i+1];
      for (int c=i+2;c<16;++c) w += VT[r][c]*Lm[i][c];
      w *= tpv;
      VT[r][i+1] -= w;
      for (int c=i+2;c<16;++c) VT[r][c] -= w*Lm[i][c];
    }
    __syncthreads();
  }
  if (l<16){
    int r=l;
    for (int j=15;j>=0;--j){
      double s = VT[r][j];
      for (int k=j+1;k<16;++k) s -= A1[r][k]*Lg[k*16+j];
      A1[r][j] = s*frcp1(Lg[j*16+j]);
    }
    for (int j=0;j<16;++j) Wout[r*16+j] = A1[r][j];
  }
  #undef Dv
  #undef Ev
}

// Vh = W @ B ; write R (4096x16) and Rinv (16x4096)
__global__ __launch_bounds__(256) void k_formVh2(const float* __restrict__ B, const double* __restrict__ W,
                                                 float* __restrict__ outR, float* __restrict__ outRinv){
  __shared__ double sW[256];
  int t = threadIdx.x;
  sW[t] = W[t];
  __syncthreads();
  int d = blockIdx.x*256 + t;
  double bi[16];
  #pragma unroll
  for (int i=0;i<16;++i) bi[i] = (double)B[(size_t)i*DDIM + d];
  #pragma unroll
  for (int r=0;r<16;++r){
    double s = 0.0;
    #pragma unroll
    for (int i=0;i<16;++i) s += sW[r*16+i]*bi[i];
    float f = (float)s;
    outRinv[(size_t)r*DDIM + d] = f;
    outR[(size_t)d*16 + r] = f;
  }
}

// ---------------- silu (fallback: last, frees scratch region) ----------------
__global__ void k_silu(const float4* __restrict__ x4, float4* __restrict__ o4){
  int tid = blockIdx.x*blockDim.x + threadIdx.x;
  int stride = gridDim.x*blockDim.x;
  for (int i = tid; i < N_TOTAL/4; i += stride){
    float4 v = x4[i];
    float4 o;
    o.x = v.x / (1.0f + expf(-v.x));
    o.y = v.y / (1.0f + expf(-v.y));
    o.z = v.z / (1.0f + expf(-v.z));
    o.w = v.w / (1.0f + expf(-v.w));
    o4[i] = o;
  }
}

// ---------------- launch ----------------
extern "C" void kernel_launch(void* const* d_in, const int* in_sizes, int n_in,
                              void* d_out, int out_size, void* d_ws, size_t ws_size,
                              hipStream_t stream) {
  (void)in_sizes; (void)n_in; (void)out_size;
  const float* x = (const float*)d_in[0];
  float* out = (float*)d_out;
  const size_t NEEDED = 20512832;  // bytes of scratch (ends at partG end)
  const bool useWs = (d_ws != nullptr) && (ws_size >= NEEDED);
  float* scr = useWs ? (float*)d_ws : out;
  // scratch layout (float offsets from scr)
  unsigned* h1   = (unsigned*)scr;                 // [0, 4096)
  unsigned* h2   = (unsigned*)(scr + 4096);        // [4096, 528384)
  unsigned* ctr  = (unsigned*)(scr + 528384);      // counters (memset'd)
  unsigned* selu = (unsigned*)(scr + 528400);
  float*    self = (float*)selu;
  unsigned* gs   = (unsigned*)(scr + 528496);      // 1024 group sums
  float* Om = scr + 532496;                        // 65536
  float* Y  = scr + 598032;                        // 131072
  float* T  = scr + 729104;                        // 65536
  float* B  = scr + 794640;                        // 65536
  double* dsm  = (double*)(scr + 860192);          // f64 area (byte ofs %8==0)
  double* Ld   = dsm;
  double* Uinvd= dsm + 256;
  double* Wd   = dsm + 512;
  double* part = (double*)(scr + 917520);          // 32*65536 doubles = 16 MB
  double* partG= (double*)(scr + 5111824);         // 32*256 doubles
  float* outScalar = out + (size_t)N_TOTAL;
  float* outR      = out + (size_t)N_TOTAL + 1;
  float* outRinv   = out + (size_t)N_TOTAL + 1 + 65536;

  hipMemsetAsync(h1, 0, (4096+524288+16)*sizeof(unsigned), stream);
  if (useWs){
    k_siluhist<<<2048,256,0,stream>>>((const float4*)x, (float4*)out, h1);
  } else {
    k_hist1<<<1024,256,0,stream>>>((const float4*)x, h1);
  }
  k_select1<<<1,1024,0,stream>>>(h1, selu);
  k_hist2<<<2048,256,0,stream>>>((const float4*)x, h2, selu);
  k_grpsum<<<1024,128,0,stream>>>((const uint4*)h2, gs);
  k_select2b<<<1,1024,0,stream>>>(gs, h2, selu, outScalar);
  k_omega<<<128,256,0,stream>>>(Om);

  // Q0 = qr(Xs @ Omega): gemmA (raw) + gram/chol; Uinv applied by consumers
  k_gemmA<<<512,256,0,stream>>>(x, Om, Y, self, Uinvd, 0);
  k_gramMC<<<32,256,0,stream>>>(Y, NROWS/32, partG, Ld, Uinvd, ctr);
  // 2 power iterations
  for (int it=0; it<2; ++it){
    k_gemmAT<<<dim3(16,NCHUNK),256,0,stream>>>(x, Y, Uinvd, part, self);          // consumes U_Y
    k_gramTR<<<32,256,0,stream>>>(part, T, partG, Ld, Uinvd, ctr);                 // writes T, U_T
    k_gemmA<<<512,256,0,stream>>>(x, T, Y, self, Uinvd, 1);                        // consumes U_T
    k_gramMC<<<32,256,0,stream>>>(Y, NROWS/32, partG, Ld, Uinvd, ctr);             // U_Y
  }
  // B = Q^T Xs
  k_gemmAT<<<dim3(16,NCHUNK),256,0,stream>>>(x, Y, Uinvd, part, self);
  k_gramBR<<<16,256,0,stream>>>(part, B, partG, Ld, Uinvd, ctr);                   // writes B, Ld
  k_smallsvd<<<1,64,0,stream>>>(Ld, Wd);
  k_formVh2<<<16,256,0,stream>>>(B, Wd, outR, outRinv);
  if (!useWs){
    k_silu<<<2048,256,0,stream>>>((const float4*)x, (float4*)out);
  }
}

// Round 14
// 1114.060 us; speedup vs baseline: 1.0298x; 1.0298x over previous
//
#include <hip/hip_runtime.h>
#include <math.h>

// EfficientMemorySiLU: silu + exact 0.99-quantile + faithful f64 replication of
// jax's randomized SVD (CholeskyQR power iteration + bdsqr small SVD).
// R13 -> R14: revert the applyRinv fold (512 blocks each recomputed the same
// W*Uinv: ~537M redundant f64 FMA, +57us measured). Keep the reduceT fusion
// (k_gramTR/k_gramBR) -- proven bit-identical by R13's absmax. 26 dispatches,
// R12 per-kernel work.

#define N_TOTAL 33554432
#define DDIM    4096
#define NROWS   8192
#define NCHUNK  32
#define RTARGET 33218888u   // f32(0.99)*f32(33554431) == 33218888.0 exactly

// ---------------- fast f64 helpers ----------------
__device__ __forceinline__ double frcp(double x){
  double r = (double)(1.0f/(float)x);
  r = r*(2.0 - x*r);
  r = r*(2.0 - x*r);
  return r;
}
__device__ __forceinline__ double frsqrt(double x){
  double r = (double)rsqrtf((float)x);
  double hx = 0.5*x;
  r = r*(1.5 - hx*r*r);
  r = r*(1.5 - hx*r*r);
  return r;
}
__device__ __forceinline__ double fsqrt(double x){
  return (x == 0.0) ? 0.0 : x*frsqrt(x);
}
__device__ __forceinline__ double frcp1(double x){
  double r = (double)(1.0f/(float)x);
  r = r*(2.0 - x*r);
  return r;
}
__device__ __forceinline__ double frsqrt1(double x){
  double r = (double)rsqrtf((float)x);
  r = r*(1.5 - (0.5*x)*r*r);
  return r;
}
__device__ __forceinline__ double fsqrt1(double x){
  return (x == 0.0) ? 0.0 : x*frsqrt1(x);
}

__device__ __forceinline__ double dsign(double a, double b){ return (b >= 0.0) ? fabs(a) : -fabs(a); }

__device__ __forceinline__ void f_slartg(double f, double g, double& c, double& s, double& r){
  if (g == 0.0){ c=1.0; s=0.0; r=f; }
  else if (f == 0.0){ c=0.0; s=dsign(1.0,g); r=fabs(g); }
  else {
    double d2 = f*f+g*g;
    double inv = frsqrt1(d2);
    c = fabs(f)*inv;
    r = dsign(d2*inv, f);
    s = g*inv*dsign(1.0,f);
  }
}

__device__ void f_slas2(double f, double g, double h, double& ssmin, double& ssmax){
  double fa=fabs(f), ga=fabs(g), ha=fabs(h);
  double fhmn=fmin(fa,ha), fhmx=fmax(fa,ha);
  if (fhmn == 0.0){
    ssmin=0.0;
    if (fhmx==0.0) ssmax=ga;
    else { double mx=fmax(fhmx,ga), mn=fmin(fhmx,ga); double q=mn*frcp1(mx); ssmax = mx*fsqrt1(1.0+q*q); }
  } else {
    if (ga < fhmx){
      double rinv = frcp1(fhmx);
      double as_=1.0+fhmn*rinv, at=(fhmx-fhmn)*rinv, au=ga*rinv; au=au*au;
      double c=2.0*frcp1(fsqrt1(as_*as_+au)+fsqrt1(at*at+au));
      ssmin=fhmn*c; ssmax=fhmx*frcp1(c);
    } else {
      double au=fhmx*frcp1(ga);
      if (au==0.0){ ssmin=(fhmn*fhmx)*frcp1(ga); ssmax=ga; }
      else {
        double rinv = frcp1(fhmx);
        double as_=1.0+fhmn*rinv, at=(fhmx-fhmn)*rinv;
        double c=frcp1(fsqrt1(1.0+(as_*au)*(as_*au))+fsqrt1(1.0+(at*au)*(at*au)));
        ssmin=(fhmn*c)*au; ssmin=ssmin+ssmin; ssmax=ga*frcp1(c+c);
      }
    }
  }
}

__device__ void f_slasv2(double f, double g, double h,
                         double& ssmin, double& ssmax, double& snr, double& csr, double& snl, double& csl){
  const double EPSd = 5.9604645e-8;
  double ft=f, fa=fabs(f), ht=h, ha=fabs(h);
  int pmax=1;
  bool swap_=(ha>fa);
  if (swap_){ pmax=3; double t=ft; ft=ht; ht=t; t=fa; fa=ha; ha=t; }
  double gt=g, ga=fabs(g);
  double clt=0, crt=0, slt=0, srt=0;
  if (ga == 0.0){ ssmin=ha; ssmax=fa; clt=1; crt=1; slt=0; srt=0; }
  else {
    bool gasmal=true;
    if (ga > fa){
      pmax=2;
      if ((fa*frcp1(ga)) < EPSd){
        gasmal=false;
        ssmax=ga;
        ssmin = (ha>1.0) ? (fa*frcp1(ga*frcp1(ha))) : ((fa*frcp1(ga))*ha);
        clt=1; slt=ht*frcp1(gt); srt=1; crt=ft*frcp1(gt);
      }
    }
    if (gasmal){
      double d_=fa-ha;
      double fainv = frcp1(fa);
      double l_=(d_==fa)?1.0:(d_*fainv);
      double m_=gt*frcp1(ft);
      double t_=2.0-l_;
      double mm=m_*m_, tt=t_*t_;
      double s_=fsqrt1(tt+mm);
      double r_=(l_==0.0)?fabs(m_):fsqrt1(l_*l_+mm);
      double a_=0.5*(s_+r_);
      double ainv = frcp1(a_);
      ssmin=ha*ainv;
      ssmax=fa*a_;
      if (mm==0.0){
        t_=(l_==0.0)?(dsign(2.0,ft)*dsign(1.0,gt)):(gt*frcp1(dsign(d_,ft))+m_*frcp1(t_));
      } else {
        t_=(m_*frcp1(s_+t_)+m_*frcp1(r_+l_))*(1.0+a_);
      }
      l_=fsqrt1(t_*t_+4.0);
      double linv = frcp1(l_);
      crt=2.0*linv;
      srt=t_*linv;
      clt=(crt+srt*m_)*ainv;
      slt=(ht*frcp1(ft))*srt*ainv;
    }
  }
  if (swap_){ csl=srt; snl=crt; csr=slt; snr=clt; }
  else { csl=clt; snl=slt; csr=crt; snr=srt; }
  double tsign=0.0;
  if (pmax==1) tsign = dsign(1.0,csr)*dsign(1.0,csl)*dsign(1.0,f);
  if (pmax==2) tsign = dsign(1.0,snr)*dsign(1.0,csl)*dsign(1.0,g);
  if (pmax==3) tsign = dsign(1.0,snr)*dsign(1.0,snl)*dsign(1.0,h);
  ssmax = dsign(ssmax, tsign);
  ssmin = dsign(ssmin, tsign*dsign(1.0,f)*dsign(1.0,h));
}

// ---------------- histogram / selection ----------------
__global__ __launch_bounds__(256) void k_hist1(const float4* __restrict__ x4, unsigned* __restrict__ h1){
  __shared__ unsigned lh[4096];
  for (int i=threadIdx.x; i<4096; i+=256) lh[i]=0u;
  __syncthreads();
  int tid = blockIdx.x*blockDim.x + threadIdx.x;
  int stride = gridDim.x*blockDim.x;
  for (int i = tid; i < N_TOTAL/4; i += stride){
    float4 v = x4[i];
    atomicAdd(&lh[(__float_as_uint(v.x)&0x7FFFFFFFu)>>19], 1u);
    atomicAdd(&lh[(__float_as_uint(v.y)&0x7FFFFFFFu)>>19], 1u);
    atomicAdd(&lh[(__float_as_uint(v.z)&0x7FFFFFFFu)>>19], 1u);
    atomicAdd(&lh[(__float_as_uint(v.w)&0x7FFFFFFFu)>>19], 1u);
  }
  __syncthreads();
  for (int i=threadIdx.x; i<4096; i+=256){ unsigned c=lh[i]; if (c) atomicAdd(&h1[i], c); }
}

__global__ __launch_bounds__(256) void k_siluhist(const float4* __restrict__ x4, float4* __restrict__ o4,
                                                  unsigned* __restrict__ h1){
  __shared__ unsigned lh[4096];
  for (int i=threadIdx.x; i<4096; i+=256) lh[i]=0u;
  __syncthreads();
  int tid = blockIdx.x*blockDim.x + threadIdx.x;
  int stride = gridDim.x*blockDim.x;
  for (int i = tid; i < N_TOTAL/4; i += stride){
    float4 v = x4[i];
    float4 o;
    o.x = v.x / (1.0f + expf(-v.x));
    o.y = v.y / (1.0f + expf(-v.y));
    o.z = v.z / (1.0f + expf(-v.z));
    o.w = v.w / (1.0f + expf(-v.w));
    o4[i] = o;
    atomicAdd(&lh[(__float_as_uint(v.x)&0x7FFFFFFFu)>>19], 1u);
    atomicAdd(&lh[(__float_as_uint(v.y)&0x7FFFFFFFu)>>19], 1u);
    atomicAdd(&lh[(__float_as_uint(v.z)&0x7FFFFFFFu)>>19], 1u);
    atomicAdd(&lh[(__float_as_uint(v.w)&0x7FFFFFFFu)>>19], 1u);
  }
  __syncthreads();
  for (int i=threadIdx.x; i<4096; i+=256){ unsigned c=lh[i]; if (c) atomicAdd(&h1[i], c); }
}

__global__ __launch_bounds__(1024) void k_select1(const unsigned* __restrict__ h1, unsigned* __restrict__ sel){
  __shared__ unsigned ssum[1024];
  int t = threadIdx.x;
  unsigned psum = 0;
  for (int k=0;k<4;++k) psum += h1[t*4+k];
  ssum[t]=psum; __syncthreads();
  for (int off=1; off<1024; off<<=1){
    unsigned v = (t>=off)? ssum[t-off]:0u;
    __syncthreads();
    ssum[t] += v;
    __syncthreads();
  }
  unsigned incl = ssum[t], excl = incl - psum;
  if (excl <= RTARGET && RTARGET < incl){
    unsigned run = excl;
    for (int k=0;k<4;++k){
      unsigned c = h1[t*4+k];
      if (run + c > RTARGET){ sel[1]=(unsigned)(t*4+k); sel[2]=RTARGET-run; break; }
      run += c;
    }
  }
}

__global__ void k_hist2(const float4* __restrict__ x4, unsigned* __restrict__ h2, const unsigned* __restrict__ sel){
  unsigned hstar = sel[1];
  int tid = blockIdx.x*blockDim.x + threadIdx.x;
  int stride = gridDim.x*blockDim.x;
  for (int i = tid; i < N_TOTAL/4; i += stride){
    float4 v = x4[i];
    unsigned b;
    b = __float_as_uint(v.x) & 0x7FFFFFFFu; if ((b>>19)==hstar) atomicAdd(&h2[b&0x7FFFFu],1u);
    b = __float_as_uint(v.y) & 0x7FFFFFFFu; if ((b>>19)==hstar) atomicAdd(&h2[b&0x7FFFFu],1u);
    b = __float_as_uint(v.z) & 0x7FFFFFFFu; if ((b>>19)==hstar) atomicAdd(&h2[b&0x7FFFFu],1u);
    b = __float_as_uint(v.w) & 0x7FFFFFFFu; if ((b>>19)==hstar) atomicAdd(&h2[b&0x7FFFFu],1u);
  }
}

__global__ __launch_bounds__(128) void k_grpsum(const uint4* __restrict__ h2v, unsigned* __restrict__ gs){
  __shared__ unsigned red[128];
  int g = blockIdx.x, t = threadIdx.x;
  uint4 v = h2v[(size_t)g*128 + t];
  red[t] = v.x+v.y+v.z+v.w;
  __syncthreads();
  for (int off=64; off; off>>=1){ if (t<off) red[t] += red[t+off]; __syncthreads(); }
  if (t==0) gs[g] = red[0];
}

__global__ __launch_bounds__(1024) void k_select2b(const unsigned* __restrict__ gs, const unsigned* __restrict__ h2,
                                                   unsigned* __restrict__ sel, float* __restrict__ outScalar){
  __shared__ unsigned ssum[1024];
  __shared__ unsigned sg[2];
  int t = threadIdx.x;
  unsigned target = sel[2], hstar = sel[1];
  unsigned psum = gs[t];
  ssum[t]=psum; __syncthreads();
  for (int off=1; off<1024; off<<=1){
    unsigned v = (t>=off)? ssum[t-off]:0u;
    __syncthreads();
    ssum[t] += v;
    __syncthreads();
  }
  unsigned incl = ssum[t], excl = incl - psum;
  if (excl <= target && target < incl){ sg[0]=(unsigned)t; sg[1]=excl; }
  __syncthreads();
  unsigned g = sg[0], gexcl = sg[1];
  unsigned cnt = (t<512) ? h2[(size_t)g*512 + t] : 0u;
  __syncthreads();
  ssum[t]=cnt; __syncthreads();
  for (int off=1; off<1024; off<<=1){
    unsigned v = (t>=off)? ssum[t-off]:0u;
    __syncthreads();
    ssum[t] += v;
    __syncthreads();
  }
  unsigned incl2 = ssum[t], excl2 = incl2 - cnt;
  unsigned rem = target - gexcl;
  if (t < 512 && excl2 <= rem && rem < incl2){
    unsigned tb = (hstar<<19) | (g*512 + (unsigned)t);
    float tv = __uint_as_float(tb);
    ((float*)sel)[0] = tv;
    *outScalar = tv;
  }
}

// ---------------- Omega: exact jax.random.normal(key(42),(4096,16)) ----------------
__device__ __forceinline__ unsigned rotl32(unsigned x, int r){ return (x<<r)|(x>>(32-r)); }

__device__ __forceinline__ float bits_to_normal(unsigned g){
  float u01 = __uint_as_float((g>>9) | 0x3F800000u) - 1.0f;
  float u = __fadd_rn(__fmul_rn(u01, 2.0f), -0.99999994f);
  u = fmaxf(-0.99999994f, u);
  float xx = __fmul_rn(u,u);
  float w = -log1pf(-xx);
  float p;
  if (w < 5.0f){
    w = __fadd_rn(w, -2.5f);
    p = 2.81022636e-08f;
    p = __fadd_rn(3.43273939e-07f, __fmul_rn(p,w));
    p = __fadd_rn(-3.5233877e-06f, __fmul_rn(p,w));
    p = __fadd_rn(-4.39150654e-06f, __fmul_rn(p,w));
    p = __fadd_rn(0.00021858087f, __fmul_rn(p,w));
    p = __fadd_rn(-0.00125372503f, __fmul_rn(p,w));
    p = __fadd_rn(-0.00417768164f, __fmul_rn(p,w));
    p = __fadd_rn(0.246640727f, __fmul_rn(p,w));
    p = __fadd_rn(1.50140941f, __fmul_rn(p,w));
  } else {
    w = __fadd_rn(sqrtf(w), -3.0f);
    p = -0.000200214257f;
    p = __fadd_rn(0.000100950558f, __fmul_rn(p,w));
    p = __fadd_rn(0.00134934322f, __fmul_rn(p,w));
    p = __fadd_rn(-0.00367342844f, __fmul_rn(p,w));
    p = __fadd_rn(0.00573950773f, __fmul_rn(p,w));
    p = __fadd_rn(-0.0076224613f, __fmul_rn(p,w));
    p = __fadd_rn(0.00943887047f, __fmul_rn(p,w));
    p = __fadd_rn(1.00167406f, __fmul_rn(p,w));
    p = __fadd_rn(2.83297682f, __fmul_rn(p,w));
  }
  return __fmul_rn(__uint_as_float(0x3FB504F3u), __fmul_rn(p,u));
}

#define TF_ROUND(r) { x0 += x1; x1 = rotl32(x1,(r)); x1 ^= x0; }

__global__ void k_omega(float* __restrict__ om){
  unsigned p = blockIdx.x*blockDim.x + threadIdx.x;
  unsigned x0 = p, x1 = 32768u + p;
  const unsigned ks0 = 0u, ks1 = 42u, ks2 = 0x1BD11BDAu ^ 0u ^ 42u;
  x0 += ks0; x1 += ks1;
  TF_ROUND(13) TF_ROUND(15) TF_ROUND(26) TF_ROUND(6)   x0+=ks1; x1+=ks2+1u;
  TF_ROUND(17) TF_ROUND(29) TF_ROUND(16) TF_ROUND(24)  x0+=ks2; x1+=ks0+2u;
  TF_ROUND(13) TF_ROUND(15) TF_ROUND(26) TF_ROUND(6)   x0+=ks0; x1+=ks1+3u;
  TF_ROUND(17) TF_ROUND(29) TF_ROUND(16) TF_ROUND(24)  x0+=ks1; x1+=ks2+4u;
  TF_ROUND(13) TF_ROUND(15) TF_ROUND(26) TF_ROUND(6)   x0+=ks2; x1+=ks0+5u;
  om[p]         = bits_to_normal(x0);
  om[p+32768u]  = bits_to_normal(x1);
}

// ---------------- GEMMs (f64 accumulation; f32 LDS staging) ----------------
__global__ __launch_bounds__(256) void k_gemmA(const float* __restrict__ x, const float* __restrict__ W,
                                               float* __restrict__ Y, const float* __restrict__ sel){
  __shared__ float xs[16][128];
  __shared__ float ws[128][16];
  const float t = sel[0];
  const int tid = threadIdx.x;
  const int c = tid & 15, rl = tid >> 4;
  const int row0 = blockIdx.x*16;
  const int c8 = c*8;
  const int wk = (tid*8) >> 4, wc = (tid*8) & 15;
  double acc = 0.0;
  for (int kt = 0; kt < DDIM; kt += 128){
    const float4* p = (const float4*)(x + (size_t)(row0+rl)*DDIM + kt + c8);
    float4 a = p[0], b = p[1];
    xs[rl][c8+0] = (fabsf(a.x) > t) ? 0.0f : a.x;
    xs[rl][c8+1] = (fabsf(a.y) > t) ? 0.0f : a.y;
    xs[rl][c8+2] = (fabsf(a.z) > t) ? 0.0f : a.z;
    xs[rl][c8+3] = (fabsf(a.w) > t) ? 0.0f : a.w;
    xs[rl][c8+4] = (fabsf(b.x) > t) ? 0.0f : b.x;
    xs[rl][c8+5] = (fabsf(b.y) > t) ? 0.0f : b.y;
    xs[rl][c8+6] = (fabsf(b.z) > t) ? 0.0f : b.z;
    xs[rl][c8+7] = (fabsf(b.w) > t) ? 0.0f : b.w;
    const float4* q = (const float4*)(W + (size_t)kt*16 + tid*8);
    float4 wa = q[0], wb = q[1];
    float* dstw = &ws[wk][wc];
    dstw[0]=wa.x; dstw[1]=wa.y; dstw[2]=wa.z; dstw[3]=wa.w;
    dstw[4]=wb.x; dstw[5]=wb.y; dstw[6]=wb.z; dstw[7]=wb.w;
    __syncthreads();
    #pragma unroll
    for (int k=0;k<128;k+=2){
      float2 xv2 = *(const float2*)&xs[rl][k];
      acc += (double)xv2.x*(double)ws[k][c];
      acc += (double)xv2.y*(double)ws[k+1][c];
    }
    __syncthreads();
  }
  Y[(size_t)(row0+rl)*16 + c] = (float)acc;
}

__global__ __launch_bounds__(256) void k_gemmAT(const float* __restrict__ x, const float* __restrict__ Q,
                                                double* __restrict__ part, const float* __restrict__ sel){
  __shared__ float qs[128][16];
  const float t = sel[0];
  const int tid = threadIdx.x;
  const int d = blockIdx.x*256 + tid;
  const int chunk = blockIdx.y;
  const int i0 = chunk*(NROWS/NCHUNK);
  double acc[16];
  #pragma unroll
  for (int c=0;c<16;++c) acc[c]=0.0;
  for (int it=0; it<NROWS/NCHUNK; it+=128){
    if (tid < 128){
      const float4* src = (const float4*)(Q + (size_t)(i0+it+tid)*16);
      float4 a = src[0], b = src[1], c4 = src[2], d4 = src[3];
      float* dst = &qs[tid][0];
      dst[0]=a.x; dst[1]=a.y; dst[2]=a.z; dst[3]=a.w;
      dst[4]=b.x; dst[5]=b.y; dst[6]=b.z; dst[7]=b.w;
      dst[8]=c4.x; dst[9]=c4.y; dst[10]=c4.z; dst[11]=c4.w;
      dst[12]=d4.x; dst[13]=d4.y; dst[14]=d4.z; dst[15]=d4.w;
    }
    __syncthreads();
    for (int ii=0; ii<128; ++ii){
      float xv = x[(size_t)(i0+it+ii)*DDIM + d];
      xv = (fabsf(xv) > t) ? 0.0f : xv;
      double xd = (double)xv;
      #pragma unroll
      for (int c2=0;c2<8;++c2){
        float2 q2 = *(const float2*)&qs[ii][c2*2];
        acc[c2*2]   += xd*(double)q2.x;
        acc[c2*2+1] += xd*(double)q2.y;
      }
    }
    __syncthreads();
  }
  double* pp = part + ((size_t)chunk*DDIM + d)*16;
  #pragma unroll
  for (int c=0;c<16;++c) pp[c]=acc[c];
}

// ---------------- CholeskyQR building blocks ----------------
__device__ void redchol_body(const double* part, int nchunks, double* Lout, double* Uinv,
                             double (*Gs)[17], double (*Vs)[17], int t){
  {
    double s = 0.0;
    for (int c=0;c<nchunks;++c) s += part[(size_t)c*256 + t];
    Gs[t>>4][t&15] = s;
  }
  __syncthreads();
  int l = t;
  for (int k=0;k<16;++k){
    if (l==k) Gs[k][k] = fsqrt(Gs[k][k]);
    __syncthreads();
    if (l>k && l<16) Gs[k][l] = Gs[k][l]*frcp(Gs[k][k]);
    __syncthreads();
    if (l>k && l<16){
      double g = Gs[k][l];
      for (int i=k+1;i<=l;++i) Gs[i][l] -= Gs[k][i]*g;
    }
    __syncthreads();
  }
  if (l<16){
    for (int i=0;i<16;++i) Vs[i][l] = 0.0;
    Vs[l][l] = frcp(Gs[l][l]);
    for (int i=l-1;i>=0;--i){
      double s = 0.0;
      for (int k=i+1;k<=l;++k) s += Gs[i][k]*Vs[k][l];
      Vs[i][l] = -s*frcp(Gs[i][i]);
    }
  }
  __syncthreads();
  if (l<16){
    for (int c=0;c<16;++c){
      Lout[l*16+c] = (c<=l) ? Gs[c][l] : 0.0;
      Uinv[l*16+c] = (l<=c) ? Vs[l][c] : 0.0;
    }
  }
}

__global__ __launch_bounds__(256) void k_gramMC(const float* __restrict__ M, int rowsPerChunk,
                                                double* __restrict__ part,
                                                double* __restrict__ Lout, double* __restrict__ Uinv,
                                                unsigned* __restrict__ ctr){
  __shared__ float lds[16][17];
  __shared__ double Gs[16][17];
  __shared__ double Vs[16][17];
  __shared__ unsigned slast;
  int t = threadIdx.x; int i = t>>4, j = t&15;
  int r0 = blockIdx.x*rowsPerChunk;
  double acc = 0.0;
  for (int rt=0; rt<rowsPerChunk; rt+=16){
    lds[t>>4][t&15] = M[(size_t)(r0+rt+(t>>4))*16 + (t&15)];
    __syncthreads();
    #pragma unroll
    for (int dd2=0; dd2<16; ++dd2) acc += (double)lds[dd2][i]*(double)lds[dd2][j];
    __syncthreads();
  }
  part[(size_t)blockIdx.x*256 + t] = acc;
  __threadfence();
  if (t==0) slast = atomicAdd(ctr, 1u);
  __syncthreads();
  if (slast != gridDim.x-1u) return;
  __threadfence();
  redchol_body(part, (int)gridDim.x, Lout, Uinv, Gs, Vs, t);
  __syncthreads();
  if (t==0) *ctr = 0u;
}

// fused: reduce partials -> T (f32, written) -> gram (gramMC order) -> last-block redchol
__global__ __launch_bounds__(256) void k_gramTR(const double* __restrict__ part, float* __restrict__ T,
                                                double* __restrict__ partG,
                                                double* __restrict__ Lout, double* __restrict__ Uinv,
                                                unsigned* __restrict__ ctr){
  __shared__ float sT[128][17];
  __shared__ double Gs[16][17];
  __shared__ double Vs[16][17];
  __shared__ unsigned slast;
  int t = threadIdx.x; int i = t>>4, j = t&15;
  int b = blockIdx.x;   // 32 blocks x 128 rows
  #pragma unroll
  for (int e=0;e<8;++e){
    int idx = t + e*256;
    int row = idx >> 4, col = idx & 15;
    size_t gidx = ((size_t)(b*128 + row))*16 + col;
    double s = 0.0;
    for (int c=0;c<NCHUNK;++c) s += part[(size_t)c*DDIM*16 + gidx];
    float v = (float)s;
    sT[row][col] = v;
    T[gidx] = v;
  }
  __syncthreads();
  double acc = 0.0;
  for (int rt=0; rt<128; rt+=16){
    #pragma unroll
    for (int dd2=0; dd2<16; ++dd2) acc += (double)sT[rt+dd2][i]*(double)sT[rt+dd2][j];
  }
  partG[(size_t)b*256 + t] = acc;
  __threadfence();
  if (t==0) slast = atomicAdd(ctr, 1u);
  __syncthreads();
  if (slast != gridDim.x-1u) return;
  __threadfence();
  redchol_body(partG, (int)gridDim.x, Lout, Uinv, Gs, Vs, t);
  __syncthreads();
  if (t==0) *ctr = 0u;
}

// fused: reduce partials -> B (f32, written) -> gram over columns -> redchol
__global__ __launch_bounds__(256) void k_gramBR(const double* __restrict__ part, float* __restrict__ B,
                                                double* __restrict__ partG,
                                                double* __restrict__ Lout, double* __restrict__ Uinv,
                                                unsigned* __restrict__ ctr){
  __shared__ float sB[16][257];
  __shared__ double Gs[16][17];
  __shared__ double Vs[16][17];
  __shared__ unsigned slast;
  int t = threadIdx.x; int i = t>>4, j = t&15;
  int b = blockIdx.x; int d0 = b*256;   // 16 blocks x 256 cols
  #pragma unroll
  for (int e=0;e<16;++e){
    int idx = t + e*256;
    int r = idx >> 8;
    int dl = idx & 255;
    size_t gidx = ((size_t)(d0+dl))*16 + r;
    double s = 0.0;
    for (int c=0;c<NCHUNK;++c) s += part[(size_t)c*DDIM*16 + gidx];
    float v = (float)s;
    sB[r][dl] = v;
    B[(size_t)r*DDIM + d0+dl] = v;
  }
  __syncthreads();
  double acc = 0.0;
  for (int dt=0; dt<256; dt+=16){
    #pragma unroll
    for (int dd2=0; dd2<16; ++dd2) acc += (double)sB[i][dt+dd2]*(double)sB[j][dt+dd2];
  }
  partG[(size_t)b*256 + t] = acc;
  __threadfence();
  if (t==0) slast = atomicAdd(ctr, 1u);
  __syncthreads();
  if (slast != gridDim.x-1u) return;
  __threadfence();
  redchol_body(partG, (int)gridDim.x, Lout, Uinv, Gs, Vs, t);
  __syncthreads();
  if (t==0) *ctr = 0u;
}

__global__ __launch_bounds__(256) void k_applyRinv(float* __restrict__ M, const double* __restrict__ Uinv){
  __shared__ double su[256];
  int t = threadIdx.x;
  su[t] = Uinv[t];
  int r = blockIdx.x*16 + (t>>4);
  int j = t & 15;
  const float4* rp = (const float4*)(M + (size_t)r*16);
  float4 v0=rp[0], v1=rp[1], v2=rp[2], v3=rp[3];
  float rowv[16] = {v0.x,v0.y,v0.z,v0.w, v1.x,v1.y,v1.z,v1.w,
                    v2.x,v2.y,v2.z,v2.w, v3.x,v3.y,v3.z,v3.w};
  __syncthreads();
  double acc = 0.0;
  #pragma unroll
  for (int k=0;k<16;++k) acc += (double)rowv[k]*su[k*16+j];
  M[(size_t)r*16 + j] = (float)acc;
}

// ---------------- small SVD core (R8/R11 structure) ----------------
__global__ __launch_bounds__(64) void k_smallsvd(const double* __restrict__ Lg, double* __restrict__ Wout){
  __shared__ double Lm[16][16];
  __shared__ double VT[16][16];
  __shared__ double A1[16][16];
  __shared__ double dd[16], ee[16], tp[16];
  __shared__ double csv[16], snv[16];
  int l = threadIdx.x;
  for (int idx=l; idx<256; idx+=64){ int r=idx>>4, c=idx&15; Lm[r][c] = (c<=r)? Lg[r*16+c] : 0.0; }
  __syncthreads();
  for (int i=0;i<16;++i){
    double xn2=0.0;
    for (int r=i+1;r<16;++r){ double v=Lm[r][i]; xn2 += v*v; }
    double alpha = Lm[i][i];
    double beta, tauq_, scl;
    if (xn2==0.0){ tauq_=0.0; beta=alpha; scl=0.0; }
    else { beta = -dsign(fsqrt1(alpha*alpha+xn2), alpha); tauq_=(beta-alpha)*frcp1(beta); scl=frcp1(alpha-beta); }
    __syncthreads();
    if (l>i && l<16) Lm[l][i] *= scl;
    __syncthreads();
    dd[i]=beta;
    if (tauq_ != 0.0 && l>i && l<16){
      int j=l;
      double w = Lm[i][j];
      for (int r=i+1;r<16;++r) w += Lm[r][i]*Lm[r][j];
      w *= tauq_;
      Lm[i][j] -= w;
      for (int r=i+1;r<16;++r) Lm[r][j] -= w*Lm[r][i];
    }
    __syncthreads();
    if (i<15){
      double xn2b=0.0;
      for (int c=i+2;c<16;++c){ double v=Lm[i][c]; xn2b+=v*v; }
      double alpha2=Lm[i][i+1];
      double beta2, taup_, scl2;
      if (xn2b==0.0){ taup_=0.0; beta2=alpha2; scl2=0.0; }
      else { beta2=-dsign(fsqrt1(alpha2*alpha2+xn2b),alpha2); taup_=(beta2-alpha2)*frcp1(beta2); scl2=frcp1(alpha2-beta2); }
      __syncthreads();
      if (l>=i+2 && l<16) Lm[i][l] *= scl2;
      __syncthreads();
      ee[i]=beta2; tp[i]=taup_;
      if (taup_!=0.0 && l>i && l<16){
        int r=l;
        double w=Lm[r][i+1];
        for (int c=i+2;c<16;++c) w += Lm[i][c]*Lm[r][c];
        w *= taup_;
        Lm[r][i+1] -= w;
        for (int c=i+2;c<16;++c) Lm[r][c] -= w*Lm[i][c];
      }
      __syncthreads();
    } else { tp[i]=0.0; __syncthreads(); }
  }
  for (int idx=l; idx<256; idx+=64){ int r=idx>>4,c=idx&15; VT[r][c]=(r==c)?1.0:0.0; }
  __syncthreads();
  const double EPSs = 5.9604645e-8;
  const double UNFL = 1.17549435e-38;
  double tol = 10.0*EPSs;
  double sminoa, mu;
  sminoa = mu = fabs(dd[0]);
  if (sminoa != 0.0){
    for (int k=1;k<16;++k){ mu = fabs(dd[k])*(mu*frcp1(mu+fabs(ee[k-1]))); sminoa=fmin(sminoa,mu); if (sminoa==0.0) break; }
  }
  sminoa = sminoa/4.0;
  double thresh = fmax(tol*sminoa, 6.0*16.0*16.0*UNFL);
  int m=16, oldll=-1, oldm=-1, idir=0;
  double sminl=0.0;
  int guard=0;
  #define Dv(k) dd[(k)-1]
  #define Ev(k) ee[(k)-1]
  while (m > 1 && guard < 3000){
    ++guard;
    int ll=0; bool split=false;
    double smax_=fabs(Dv(m)), smin_=smax_;
    for (int lll=1; lll<=m-1; ++lll){
      ll = m-lll;
      double abss=fabs(Dv(ll)), abse=fabs(Ev(ll));
      if (abse <= thresh){ split=true; break; }
      smin_=fmin(smin_,abss); smax_=fmax(smax_,fmax(abss,abse));
    }
    if (!split) ll=0;
    else {
      Ev(ll)=0.0;
      if (ll == m-1){ m = m-1; continue; }
    }
    ll = ll+1;
    if (ll == m-1){
      double sigmn,sigmx,sinr,cosr,sinl_,cosl;
      f_slasv2(Dv(m-1), Ev(m-1), Dv(m), sigmn, sigmx, sinr, cosr, sinl_, cosl);
      Dv(m-1)=sigmx; Ev(m-1)=0.0; Dv(m)=sigmn;
      if (l<16){
        double t0 = cosr*VT[m-2][l] + sinr*VT[m-1][l];
        VT[m-1][l] = cosr*VT[m-1][l] - sinr*VT[m-2][l];
        VT[m-2][l] = t0;
      }
      __syncthreads();
      m -= 2; continue;
    }
    if (ll > oldm || m < oldll) idir = (fabs(Dv(ll)) >= fabs(Dv(m))) ? 1 : 2;
    bool cont=false;
    if (idir==1){
      if (fabs(Ev(m-1)) <= tol*fabs(Dv(m))){ Ev(m-1)=0.0; continue; }
      mu = fabs(Dv(ll)); sminl=mu;
      for (int lll=ll; lll<=m-1; ++lll){
        if (fabs(Ev(lll)) <= tol*mu){ Ev(lll)=0.0; cont=true; break; }
        mu = fabs(Dv(lll+1))*(mu*frcp1(mu+fabs(Ev(lll)))); sminl=fmin(sminl,mu);
      }
    } else {
      if (fabs(Ev(ll)) <= tol*fabs(Dv(ll))){ Ev(ll)=0.0; continue; }
      mu = fabs(Dv(m)); sminl=mu;
      for (int lll=m-1; lll>=ll; --lll){
        if (fabs(Ev(lll)) <= tol*mu){ Ev(lll)=0.0; cont=true; break; }
        mu = fabs(Dv(lll))*(mu*frcp1(mu+fabs(Ev(lll)))); sminl=fmin(sminl,mu);
      }
    }
    if (cont) continue;
    oldll=ll; oldm=m;
    double shift=0.0, rdum;
    if (!( 16.0*tol*(sminl*frcp1(smax_)) <= fmax(EPSs, 0.01*tol) )){
      double sll;
      if (idir==1){ sll=fabs(Dv(ll)); f_slas2(Dv(m-1), Ev(m-1), Dv(m), shift, rdum); }
      else        { sll=fabs(Dv(m));  f_slas2(Dv(ll), Ev(ll), Dv(ll+1), shift, rdum); }
      if (sll>0.0){ double q=shift*frcp1(sll); if (q*q < EPSs) shift=0.0; }
    }
    if (shift == 0.0){
      if (idir==1){
        double cs=1.0, oldcs=1.0, oldsn=0.0, r_;
        double dcur = Dv(ll);
        for (int i1=ll;i1<=m-1;++i1){
          double cn, snn;
          double a0 = dcur*cs;
          f_slartg(a0, Ev(i1), cn, snn, r_);
          if (i1>ll) Ev(i1-1) = oldsn*r_;
          double dnx = Dv(i1+1);
          double ocn, osn, dnew;
          f_slartg(oldcs*r_, dnx*snn, ocn, osn, dnew);
          Dv(i1)=dnew;
          cs=cn; oldcs=ocn; oldsn=osn;
          csv[i1-1]=cs; snv[i1-1]=snn;
          dcur = dnx;
        }
        double h=dcur*cs;
        Dv(m)=h*oldcs; Ev(m-1)=h*oldsn;
        if (fabs(Ev(m-1))<=thresh) Ev(m-1)=0.0;
        __syncthreads();
        if (l<16){
          double v = VT[ll-1][l];
          for (int i1=ll;i1<=m-1;++i1){
            double c=csv[i1-1], s=snv[i1-1];
            double w = VT[i1][l];
            VT[i1-1][l] = c*v + s*w;
            v = c*w - s*v;
          }
          VT[m-1][l] = v;
        }
      } else {
        double cs=1.0, oldcs=1.0, oldsn=0.0, r_;
        double dcur = Dv(m);
        for (int i1=m;i1>=ll+1;--i1){
          double cn,snn;
          double a0 = dcur*cs;
          f_slartg(a0, Ev(i1-1), cn, snn, r_);
          if (i1<m) Ev(i1)=oldsn*r_;
          double dnx = Dv(i1-1);
          double ocn,osn,dnew;
          f_slartg(oldcs*r_, dnx*snn, ocn, osn, dnew);
          Dv(i1)=dnew;
          cs=cn; oldcs=ocn; oldsn=osn;
          csv[i1-2]=oldcs; snv[i1-2]=-oldsn;
          dcur = dnx;
        }
        double h=dcur*cs;
        Dv(ll)=h*oldcs; Ev(ll)=h*oldsn;
        if (fabs(Ev(ll))<=thresh) Ev(ll)=0.0;
        __syncthreads();
        if (l<16){
          double v = VT[m-1][l];
          for (int i1=m;i1>=ll+1;--i1){
            double c=csv[i1-2], s=snv[i1-2];
            double w = VT[i1-2][l];
            VT[i1-1][l] = c*v - s*w;
            v = c*w + s*v;
          }
          VT[ll-1][l] = v;
        }
      }
    } else {
      if (idir==1){
        double f=(fabs(Dv(ll))-shift)*(dsign(1.0,Dv(ll))+shift*frcp1(Dv(ll)));
        double g=Ev(ll);
        double dcur = Dv(ll), ecur = Ev(ll);
        double r_;
        for (int i1=ll;i1<=m-1;++i1){
          double cosr,sinr,cosl,sinl_;
          double dnx = Dv(i1+1);
          f_slartg(f,g,cosr,sinr,r_);
          if (i1>ll) Ev(i1-1)=r_;
          f = cosr*dcur + sinr*ecur;
          double e_mid = cosr*ecur - sinr*dcur;
          g = sinr*dnx;
          double d_mid = cosr*dnx;
          f_slartg(f,g,cosl,sinl_,r_);
          Dv(i1)=r_;
          f = cosl*e_mid + sinl_*d_mid;
          double d_fin = cosl*d_mid - sinl_*e_mid;
          double e_fin = 0.0;
          if (i1 < m-1){ double enx = Ev(i1+1); g = sinl_*enx; e_fin = cosl*enx; }
          csv[i1-1]=cosr; snv[i1-1]=sinr;
          dcur = d_fin; ecur = e_fin;
        }
        Dv(m) = dcur;
        Ev(m-1)=f;
        if (fabs(Ev(m-1))<=thresh) Ev(m-1)=0.0;
        __syncthreads();
        if (l<16){
          double v = VT[ll-1][l];
          for (int i1=ll;i1<=m-1;++i1){
            double c=csv[i1-1], s=snv[i1-1];
            double w = VT[i1][l];
            VT[i1-1][l] = c*v + s*w;
            v = c*w - s*v;
          }
          VT[m-1][l] = v;
        }
      } else {
        double f=(fabs(Dv(m))-shift)*(dsign(1.0,Dv(m))+shift*frcp1(Dv(m)));
        double g=Ev(m-1);
        double dcur = Dv(m), ecur = Ev(m-1);
        double r_;
        for (int i1=m;i1>=ll+1;--i1){
          double cosr,sinr,cosl,sinl_;
          double dnx = Dv(i1-1);
          f_slartg(f,g,cosr,sinr,r_);
          if (i1<m) Ev(i1)=r_;
          f = cosr*dcur + sinr*ecur;
          double e_mid = cosr*ecur - sinr*dcur;
          g = sinr*dnx;
          double d_mid = cosr*dnx;
          f_slartg(f,g,cosl,sinl_,r_);
          Dv(i1)=r_;
          f = cosl*e_mid + sinl_*d_mid;
          double d_fin = cosl*d_mid - sinl_*e_mid;
          double e_fin = 0.0;
          if (i1 > ll+1){ double enx = Ev(i1-2); g = sinl_*enx; e_fin = cosl*enx; }
          csv[i1-2]=cosr; snv[i1-2]=-sinr;
          dcur = d_fin; ecur = e_fin;
        }
        Dv(ll) = dcur;
        Ev(ll)=f;
        if (fabs(Ev(ll))<=thresh) Ev(ll)=0.0;
        __syncthreads();
        if (l<16){
          double v = VT[m-1][l];
          for (int i1=m;i1>=ll+1;--i1){
            double c=csv[i1-2], s=snv[i1-2];
            double w = VT[i1-2][l];
            VT[i1-1][l] = c*v - s*w;
            v = c*w + s*v;
          }
          VT[ll-1][l] = v;
        }
      }
    }
    __syncthreads();
  }
  __syncthreads();
  for (int k=1;k<=16;++k){
    if (Dv(k) < 0.0){
      Dv(k) = -Dv(k);
      if (l<16) VT[k-1][l] = -VT[k-1][l];
    }
    __syncthreads();
  }
  for (int i1=1;i1<=15;++i1){
    int isub=1; double smn=Dv(1);
    for (int j=2;j<=17-i1;++j){ if (Dv(j) <= smn){ isub=j; smn=Dv(j);} }
    if (isub != 17-i1){
      double tmpd = Dv(17-i1);
      __syncthreads();
      Dv(isub)=tmpd; Dv(17-i1)=smn;
      if (l<16){ double t2=VT[isub-1][l]; VT[isub-1][l]=VT[16-i1][l]; VT[16-i1][l]=t2; }
    }
    __syncthreads();
  }
  for (int i=14;i>=0;--i){
    double tpv = tp[i];
    if (tpv != 0.0 && l<16){
      int r=l;
      double w = VT[r][i+1];
      for (int c=i+2;c<16;++c) w += VT[r][c]*Lm[i][c];
      w *= tpv;
      VT[r][i+1] -= w;
      for (int c=i+2;c<16;++c) VT[r][c] -= w*Lm[i][c];
    }
    __syncthreads();
  }
  if (l<16){
    int r=l;
    for (int j=15;j>=0;--j){
      double s = VT[r][j];
      for (int k=j+1;k<16;++k) s -= A1[r][k]*Lg[k*16+j];
      A1[r][j] = s*frcp1(Lg[j*16+j]);
    }
    for (int j=0;j<16;++j) Wout[r*16+j] = A1[r][j];
  }
  #undef Dv
  #undef Ev
}

// Vh = W @ B ; write R (4096x16) and Rinv (16x4096)
__global__ __launch_bounds__(256) void k_formVh2(const float* __restrict__ B, const double* __restrict__ W,
                                                 float* __restrict__ outR, float* __restrict__ outRinv){
  __shared__ double sW[256];
  int t = threadIdx.x;
  sW[t] = W[t];
  __syncthreads();
  int d = blockIdx.x*256 + t;
  double bi[16];
  #pragma unroll
  for (int i=0;i<16;++i) bi[i] = (double)B[(size_t)i*DDIM + d];
  #pragma unroll
  for (int r=0;r<16;++r){
    double s = 0.0;
    #pragma unroll
    for (int i=0;i<16;++i) s += sW[r*16+i]*bi[i];
    float f = (float)s;
    outRinv[(size_t)r*DDIM + d] = f;
    outR[(size_t)d*16 + r] = f;
  }
}

// ---------------- silu (fallback: last, frees scratch region) ----------------
__global__ void k_silu(const float4* __restrict__ x4, float4* __restrict__ o4){
  int tid = blockIdx.x*blockDim.x + threadIdx.x;
  int stride = gridDim.x*blockDim.x;
  for (int i = tid; i < N_TOTAL/4; i += stride){
    float4 v = x4[i];
    float4 o;
    o.x = v.x / (1.0f + expf(-v.x));
    o.y = v.y / (1.0f + expf(-v.y));
    o.z = v.z / (1.0f + expf(-v.z));
    o.w = v.w / (1.0f + expf(-v.w));
    o4[i] = o;
  }
}

// ---------------- launch ----------------
extern "C" void kernel_launch(void* const* d_in, const int* in_sizes, int n_in,
                              void* d_out, int out_size, void* d_ws, size_t ws_size,
                              hipStream_t stream) {
  (void)in_sizes; (void)n_in; (void)out_size;
  const float* x = (const float*)d_in[0];
  float* out = (float*)d_out;
  const size_t NEEDED = 20512832;  // bytes of scratch (ends at partG end)
  const bool useWs = (d_ws != nullptr) && (ws_size >= NEEDED);
  float* scr = useWs ? (float*)d_ws : out;
  // scratch layout (float offsets from scr)
  unsigned* h1   = (unsigned*)scr;                 // [0, 4096)
  unsigned* h2   = (unsigned*)(scr + 4096);        // [4096, 528384)
  unsigned* ctr  = (unsigned*)(scr + 528384);      // counters (memset'd)
  unsigned* selu = (unsigned*)(scr + 528400);
  float*    self = (float*)selu;
  unsigned* gs   = (unsigned*)(scr + 528496);      // 1024 group sums
  float* Om = scr + 532496;                        // 65536
  float* Y  = scr + 598032;                        // 131072
  float* T  = scr + 729104;                        // 65536
  float* B  = scr + 794640;                        // 65536
  double* dsm  = (double*)(scr + 860192);          // f64 area (byte ofs %8==0)
  double* Ld   = dsm;
  double* Uinvd= dsm + 256;
  double* Wd   = dsm + 512;
  double* part = (double*)(scr + 917520);          // 32*65536 doubles = 16 MB
  double* partG= (double*)(scr + 5111824);         // 32*256 doubles
  float* outScalar = out + (size_t)N_TOTAL;
  float* outR      = out + (size_t)N_TOTAL + 1;
  float* outRinv   = out + (size_t)N_TOTAL + 1 + 65536;

  hipMemsetAsync(h1, 0, (4096+524288+16)*sizeof(unsigned), stream);
  if (useWs){
    k_siluhist<<<2048,256,0,stream>>>((const float4*)x, (float4*)out, h1);
  } else {
    k_hist1<<<1024,256,0,stream>>>((const float4*)x, h1);
  }
  k_select1<<<1,1024,0,stream>>>(h1, selu);
  k_hist2<<<2048,256,0,stream>>>((const float4*)x, h2, selu);
  k_grpsum<<<1024,128,0,stream>>>((const uint4*)h2, gs);
  k_select2b<<<1,1024,0,stream>>>(gs, h2, selu, outScalar);
  k_omega<<<128,256,0,stream>>>(Om);

  // Q0 = qr(Xs @ Omega)
  k_gemmA<<<512,256,0,stream>>>(x, Om, Y, self);
  k_gramMC<<<32,256,0,stream>>>(Y, NROWS/32, partG, Ld, Uinvd, ctr);
  k_applyRinv<<<NROWS/16,256,0,stream>>>(Y, Uinvd);
  // 2 power iterations
  for (int it=0; it<2; ++it){
    k_gemmAT<<<dim3(16,NCHUNK),256,0,stream>>>(x, Y, part, self);
    k_gramTR<<<32,256,0,stream>>>(part, T, partG, Ld, Uinvd, ctr);     // writes T + U_T
    k_applyRinv<<<DDIM/16,256,0,stream>>>(T, Uinvd);
    k_gemmA<<<512,256,0,stream>>>(x, T, Y, self);
    k_gramMC<<<32,256,0,stream>>>(Y, NROWS/32, partG, Ld, Uinvd, ctr);
    k_applyRinv<<<NROWS/16,256,0,stream>>>(Y, Uinvd);
  }
  // B = Q^T Xs
  k_gemmAT<<<dim3(16,NCHUNK),256,0,stream>>>(x, Y, part, self);
  k_gramBR<<<16,256,0,stream>>>(part, B, partG, Ld, Uinvd, ctr);       // writes B + Ld
  k_smallsvd<<<1,64,0,stream>>>(Ld, Wd);
  k_formVh2<<<16,256,0,stream>>>(B, Wd, outR, outRinv);
  if (!useWs){
    k_silu<<<2048,256,0,stream>>>((const float4*)x, (float4*)out);
  }
}

// Round 15
// 1089.873 us; speedup vs baseline: 1.0526x; 1.0222x over previous
//
#include <hip/hip_runtime.h>
#include <math.h>

// EfficientMemorySiLU: silu + exact 0.99-quantile + faithful f64 replication of
// jax's randomized SVD (CholeskyQR power iteration + bdsqr small SVD).
// R14 -> R15: revert to the best-measured configuration (R12, 1090us).
// R13 (fold Uinv into gemms: +57us, redundant recompute) and R14 (reduceT
// fusion + applyRinv restore: +24us vs R12) showed launch-structure changes
// are inside the +-25us noise band. R12 config: f32 LDS staging gemms,
// separate reduceT + gramMC/gramBC (fused redchol), separate applyRinv,
// R11 smallsvd (serial floor ~220us).

#define N_TOTAL 33554432
#define DDIM    4096
#define NROWS   8192
#define NCHUNK  32
#define RTARGET 33218888u   // f32(0.99)*f32(33554431) == 33218888.0 exactly

// ---------------- fast f64 helpers ----------------
// 2-Newton (~0.5 ulp) — used in CholeskyQR path
__device__ __forceinline__ double frcp(double x){
  double r = (double)(1.0f/(float)x);
  r = r*(2.0 - x*r);
  r = r*(2.0 - x*r);
  return r;
}
__device__ __forceinline__ double frsqrt(double x){
  double r = (double)rsqrtf((float)x);
  double hx = 0.5*x;
  r = r*(1.5 - hx*r*r);
  r = r*(1.5 - hx*r*r);
  return r;
}
__device__ __forceinline__ double fsqrt(double x){
  return (x == 0.0) ? 0.0 : x*frsqrt(x);
}
// 1-Newton (~1.5e-14 rel) — used in the small SVD (latency-critical serial chains)
__device__ __forceinline__ double frcp1(double x){
  double r = (double)(1.0f/(float)x);
  r = r*(2.0 - x*r);
  return r;
}
__device__ __forceinline__ double frsqrt1(double x){
  double r = (double)rsqrtf((float)x);
  r = r*(1.5 - (0.5*x)*r*r);
  return r;
}
__device__ __forceinline__ double fsqrt1(double x){
  return (x == 0.0) ? 0.0 : x*frsqrt1(x);
}

__device__ __forceinline__ double dsign(double a, double b){ return (b >= 0.0) ? fabs(a) : -fabs(a); }

__device__ __forceinline__ void f_slartg(double f, double g, double& c, double& s, double& r){
  if (g == 0.0){ c=1.0; s=0.0; r=f; }
  else if (f == 0.0){ c=0.0; s=dsign(1.0,g); r=fabs(g); }
  else {
    double d2 = f*f+g*g;
    double inv = frsqrt1(d2);
    c = fabs(f)*inv;
    r = dsign(d2*inv, f);
    s = g*inv*dsign(1.0,f);
  }
}

__device__ void f_slas2(double f, double g, double h, double& ssmin, double& ssmax){
  double fa=fabs(f), ga=fabs(g), ha=fabs(h);
  double fhmn=fmin(fa,ha), fhmx=fmax(fa,ha);
  if (fhmn == 0.0){
    ssmin=0.0;
    if (fhmx==0.0) ssmax=ga;
    else { double mx=fmax(fhmx,ga), mn=fmin(fhmx,ga); double q=mn*frcp1(mx); ssmax = mx*fsqrt1(1.0+q*q); }
  } else {
    if (ga < fhmx){
      double rinv = frcp1(fhmx);
      double as_=1.0+fhmn*rinv, at=(fhmx-fhmn)*rinv, au=ga*rinv; au=au*au;
      double c=2.0*frcp1(fsqrt1(as_*as_+au)+fsqrt1(at*at+au));
      ssmin=fhmn*c; ssmax=fhmx*frcp1(c);
    } else {
      double au=fhmx*frcp1(ga);
      if (au==0.0){ ssmin=(fhmn*fhmx)*frcp1(ga); ssmax=ga; }
      else {
        double rinv = frcp1(fhmx);
        double as_=1.0+fhmn*rinv, at=(fhmx-fhmn)*rinv;
        double c=frcp1(fsqrt1(1.0+(as_*au)*(as_*au))+fsqrt1(1.0+(at*au)*(at*au)));
        ssmin=(fhmn*c)*au; ssmin=ssmin+ssmin; ssmax=ga*frcp1(c+c);
      }
    }
  }
}

__device__ void f_slasv2(double f, double g, double h,
                         double& ssmin, double& ssmax, double& snr, double& csr, double& snl, double& csl){
  const double EPSd = 5.9604645e-8;
  double ft=f, fa=fabs(f), ht=h, ha=fabs(h);
  int pmax=1;
  bool swap_=(ha>fa);
  if (swap_){ pmax=3; double t=ft; ft=ht; ht=t; t=fa; fa=ha; ha=t; }
  double gt=g, ga=fabs(g);
  double clt=0, crt=0, slt=0, srt=0;
  if (ga == 0.0){ ssmin=ha; ssmax=fa; clt=1; crt=1; slt=0; srt=0; }
  else {
    bool gasmal=true;
    if (ga > fa){
      pmax=2;
      if ((fa*frcp1(ga)) < EPSd){
        gasmal=false;
        ssmax=ga;
        ssmin = (ha>1.0) ? (fa*frcp1(ga*frcp1(ha))) : ((fa*frcp1(ga))*ha);
        clt=1; slt=ht*frcp1(gt); srt=1; crt=ft*frcp1(gt);
      }
    }
    if (gasmal){
      double d_=fa-ha;
      double fainv = frcp1(fa);
      double l_=(d_==fa)?1.0:(d_*fainv);
      double m_=gt*frcp1(ft);
      double t_=2.0-l_;
      double mm=m_*m_, tt=t_*t_;
      double s_=fsqrt1(tt+mm);
      double r_=(l_==0.0)?fabs(m_):fsqrt1(l_*l_+mm);
      double a_=0.5*(s_+r_);
      double ainv = frcp1(a_);
      ssmin=ha*ainv;
      ssmax=fa*a_;
      if (mm==0.0){
        t_=(l_==0.0)?(dsign(2.0,ft)*dsign(1.0,gt)):(gt*frcp1(dsign(d_,ft))+m_*frcp1(t_));
      } else {
        t_=(m_*frcp1(s_+t_)+m_*frcp1(r_+l_))*(1.0+a_);
      }
      l_=fsqrt1(t_*t_+4.0);
      double linv = frcp1(l_);
      crt=2.0*linv;
      srt=t_*linv;
      clt=(crt+srt*m_)*ainv;
      slt=(ht*frcp1(ft))*srt*ainv;
    }
  }
  if (swap_){ csl=srt; snl=crt; csr=slt; snr=clt; }
  else { csl=clt; snl=slt; csr=crt; snr=srt; }
  double tsign=0.0;
  if (pmax==1) tsign = dsign(1.0,csr)*dsign(1.0,csl)*dsign(1.0,f);
  if (pmax==2) tsign = dsign(1.0,snr)*dsign(1.0,csl)*dsign(1.0,g);
  if (pmax==3) tsign = dsign(1.0,snr)*dsign(1.0,snl)*dsign(1.0,h);
  ssmax = dsign(ssmax, tsign);
  ssmin = dsign(ssmin, tsign*dsign(1.0,f)*dsign(1.0,h));
}

// ---------------- histogram / selection ----------------
__global__ __launch_bounds__(256) void k_hist1(const float4* __restrict__ x4, unsigned* __restrict__ h1){
  __shared__ unsigned lh[4096];
  for (int i=threadIdx.x; i<4096; i+=256) lh[i]=0u;
  __syncthreads();
  int tid = blockIdx.x*blockDim.x + threadIdx.x;
  int stride = gridDim.x*blockDim.x;
  for (int i = tid; i < N_TOTAL/4; i += stride){
    float4 v = x4[i];
    atomicAdd(&lh[(__float_as_uint(v.x)&0x7FFFFFFFu)>>19], 1u);
    atomicAdd(&lh[(__float_as_uint(v.y)&0x7FFFFFFFu)>>19], 1u);
    atomicAdd(&lh[(__float_as_uint(v.z)&0x7FFFFFFFu)>>19], 1u);
    atomicAdd(&lh[(__float_as_uint(v.w)&0x7FFFFFFFu)>>19], 1u);
  }
  __syncthreads();
  for (int i=threadIdx.x; i<4096; i+=256){ unsigned c=lh[i]; if (c) atomicAdd(&h1[i], c); }
}

__global__ __launch_bounds__(256) void k_siluhist(const float4* __restrict__ x4, float4* __restrict__ o4,
                                                  unsigned* __restrict__ h1){
  __shared__ unsigned lh[4096];
  for (int i=threadIdx.x; i<4096; i+=256) lh[i]=0u;
  __syncthreads();
  int tid = blockIdx.x*blockDim.x + threadIdx.x;
  int stride = gridDim.x*blockDim.x;
  for (int i = tid; i < N_TOTAL/4; i += stride){
    float4 v = x4[i];
    float4 o;
    o.x = v.x / (1.0f + expf(-v.x));
    o.y = v.y / (1.0f + expf(-v.y));
    o.z = v.z / (1.0f + expf(-v.z));
    o.w = v.w / (1.0f + expf(-v.w));
    o4[i] = o;
    atomicAdd(&lh[(__float_as_uint(v.x)&0x7FFFFFFFu)>>19], 1u);
    atomicAdd(&lh[(__float_as_uint(v.y)&0x7FFFFFFFu)>>19], 1u);
    atomicAdd(&lh[(__float_as_uint(v.z)&0x7FFFFFFFu)>>19], 1u);
    atomicAdd(&lh[(__float_as_uint(v.w)&0x7FFFFFFFu)>>19], 1u);
  }
  __syncthreads();
  for (int i=threadIdx.x; i<4096; i+=256){ unsigned c=lh[i]; if (c) atomicAdd(&h1[i], c); }
}

__global__ __launch_bounds__(1024) void k_select1(const unsigned* __restrict__ h1, unsigned* __restrict__ sel){
  __shared__ unsigned ssum[1024];
  int t = threadIdx.x;
  unsigned psum = 0;
  for (int k=0;k<4;++k) psum += h1[t*4+k];
  ssum[t]=psum; __syncthreads();
  for (int off=1; off<1024; off<<=1){
    unsigned v = (t>=off)? ssum[t-off]:0u;
    __syncthreads();
    ssum[t] += v;
    __syncthreads();
  }
  unsigned incl = ssum[t], excl = incl - psum;
  if (excl <= RTARGET && RTARGET < incl){
    unsigned run = excl;
    for (int k=0;k<4;++k){
      unsigned c = h1[t*4+k];
      if (run + c > RTARGET){ sel[1]=(unsigned)(t*4+k); sel[2]=RTARGET-run; break; }
      run += c;
    }
  }
}

__global__ void k_hist2(const float4* __restrict__ x4, unsigned* __restrict__ h2, const unsigned* __restrict__ sel){
  unsigned hstar = sel[1];
  int tid = blockIdx.x*blockDim.x + threadIdx.x;
  int stride = gridDim.x*blockDim.x;
  for (int i = tid; i < N_TOTAL/4; i += stride){
    float4 v = x4[i];
    unsigned b;
    b = __float_as_uint(v.x) & 0x7FFFFFFFu; if ((b>>19)==hstar) atomicAdd(&h2[b&0x7FFFFu],1u);
    b = __float_as_uint(v.y) & 0x7FFFFFFFu; if ((b>>19)==hstar) atomicAdd(&h2[b&0x7FFFFu],1u);
    b = __float_as_uint(v.z) & 0x7FFFFFFFu; if ((b>>19)==hstar) atomicAdd(&h2[b&0x7FFFFu],1u);
    b = __float_as_uint(v.w) & 0x7FFFFFFFu; if ((b>>19)==hstar) atomicAdd(&h2[b&0x7FFFFu],1u);
  }
}

__global__ __launch_bounds__(128) void k_grpsum(const uint4* __restrict__ h2v, unsigned* __restrict__ gs){
  __shared__ unsigned red[128];
  int g = blockIdx.x, t = threadIdx.x;
  uint4 v = h2v[(size_t)g*128 + t];
  red[t] = v.x+v.y+v.z+v.w;
  __syncthreads();
  for (int off=64; off; off>>=1){ if (t<off) red[t] += red[t+off]; __syncthreads(); }
  if (t==0) gs[g] = red[0];
}

__global__ __launch_bounds__(1024) void k_select2b(const unsigned* __restrict__ gs, const unsigned* __restrict__ h2,
                                                   unsigned* __restrict__ sel, float* __restrict__ outScalar){
  __shared__ unsigned ssum[1024];
  __shared__ unsigned sg[2];
  int t = threadIdx.x;
  unsigned target = sel[2], hstar = sel[1];
  unsigned psum = gs[t];
  ssum[t]=psum; __syncthreads();
  for (int off=1; off<1024; off<<=1){
    unsigned v = (t>=off)? ssum[t-off]:0u;
    __syncthreads();
    ssum[t] += v;
    __syncthreads();
  }
  unsigned incl = ssum[t], excl = incl - psum;
  if (excl <= target && target < incl){ sg[0]=(unsigned)t; sg[1]=excl; }
  __syncthreads();
  unsigned g = sg[0], gexcl = sg[1];
  unsigned cnt = (t<512) ? h2[(size_t)g*512 + t] : 0u;
  __syncthreads();
  ssum[t]=cnt; __syncthreads();
  for (int off=1; off<1024; off<<=1){
    unsigned v = (t>=off)? ssum[t-off]:0u;
    __syncthreads();
    ssum[t] += v;
    __syncthreads();
  }
  unsigned incl2 = ssum[t], excl2 = incl2 - cnt;
  unsigned rem = target - gexcl;
  if (t < 512 && excl2 <= rem && rem < incl2){
    unsigned tb = (hstar<<19) | (g*512 + (unsigned)t);
    float tv = __uint_as_float(tb);
    ((float*)sel)[0] = tv;
    *outScalar = tv;
  }
}

// ---------------- Omega: exact jax.random.normal(key(42),(4096,16)) ----------------
__device__ __forceinline__ unsigned rotl32(unsigned x, int r){ return (x<<r)|(x>>(32-r)); }

__device__ __forceinline__ float bits_to_normal(unsigned g){
  float u01 = __uint_as_float((g>>9) | 0x3F800000u) - 1.0f;
  float u = __fadd_rn(__fmul_rn(u01, 2.0f), -0.99999994f);
  u = fmaxf(-0.99999994f, u);
  float xx = __fmul_rn(u,u);
  float w = -log1pf(-xx);
  float p;
  if (w < 5.0f){
    w = __fadd_rn(w, -2.5f);
    p = 2.81022636e-08f;
    p = __fadd_rn(3.43273939e-07f, __fmul_rn(p,w));
    p = __fadd_rn(-3.5233877e-06f, __fmul_rn(p,w));
    p = __fadd_rn(-4.39150654e-06f, __fmul_rn(p,w));
    p = __fadd_rn(0.00021858087f, __fmul_rn(p,w));
    p = __fadd_rn(-0.00125372503f, __fmul_rn(p,w));
    p = __fadd_rn(-0.00417768164f, __fmul_rn(p,w));
    p = __fadd_rn(0.246640727f, __fmul_rn(p,w));
    p = __fadd_rn(1.50140941f, __fmul_rn(p,w));
  } else {
    w = __fadd_rn(sqrtf(w), -3.0f);
    p = -0.000200214257f;
    p = __fadd_rn(0.000100950558f, __fmul_rn(p,w));
    p = __fadd_rn(0.00134934322f, __fmul_rn(p,w));
    p = __fadd_rn(-0.00367342844f, __fmul_rn(p,w));
    p = __fadd_rn(0.00573950773f, __fmul_rn(p,w));
    p = __fadd_rn(-0.0076224613f, __fmul_rn(p,w));
    p = __fadd_rn(0.00943887047f, __fmul_rn(p,w));
    p = __fadd_rn(1.00167406f, __fmul_rn(p,w));
    p = __fadd_rn(2.83297682f, __fmul_rn(p,w));
  }
  return __fmul_rn(__uint_as_float(0x3FB504F3u), __fmul_rn(p,u));
}

#define TF_ROUND(r) { x0 += x1; x1 = rotl32(x1,(r)); x1 ^= x0; }

__global__ void k_omega(float* __restrict__ om){
  unsigned p = blockIdx.x*blockDim.x + threadIdx.x;
  unsigned x0 = p, x1 = 32768u + p;
  const unsigned ks0 = 0u, ks1 = 42u, ks2 = 0x1BD11BDAu ^ 0u ^ 42u;
  x0 += ks0; x1 += ks1;
  TF_ROUND(13) TF_ROUND(15) TF_ROUND(26) TF_ROUND(6)   x0+=ks1; x1+=ks2+1u;
  TF_ROUND(17) TF_ROUND(29) TF_ROUND(16) TF_ROUND(24)  x0+=ks2; x1+=ks0+2u;
  TF_ROUND(13) TF_ROUND(15) TF_ROUND(26) TF_ROUND(6)   x0+=ks0; x1+=ks1+3u;
  TF_ROUND(17) TF_ROUND(29) TF_ROUND(16) TF_ROUND(24)  x0+=ks1; x1+=ks2+4u;
  TF_ROUND(13) TF_ROUND(15) TF_ROUND(26) TF_ROUND(6)   x0+=ks2; x1+=ks0+5u;
  om[p]         = bits_to_normal(x0);
  om[p+32768u]  = bits_to_normal(x1);
}

// ---------------- GEMMs (f64 accumulation; f32 LDS staging, exact cvt) ----------------
__global__ __launch_bounds__(256) void k_gemmA(const float* __restrict__ x, const float* __restrict__ W,
                                               float* __restrict__ Y, const float* __restrict__ sel){
  __shared__ float xs[16][128];
  __shared__ float ws[128][16];
  const float t = sel[0];
  const int tid = threadIdx.x;
  const int c = tid & 15, rl = tid >> 4;
  const int row0 = blockIdx.x*16;
  const int c8 = c*8;
  const int wk = (tid*8) >> 4, wc = (tid*8) & 15;
  double acc = 0.0;
  for (int kt = 0; kt < DDIM; kt += 128){
    const float4* p = (const float4*)(x + (size_t)(row0+rl)*DDIM + kt + c8);
    float4 a = p[0], b = p[1];
    xs[rl][c8+0] = (fabsf(a.x) > t) ? 0.0f : a.x;
    xs[rl][c8+1] = (fabsf(a.y) > t) ? 0.0f : a.y;
    xs[rl][c8+2] = (fabsf(a.z) > t) ? 0.0f : a.z;
    xs[rl][c8+3] = (fabsf(a.w) > t) ? 0.0f : a.w;
    xs[rl][c8+4] = (fabsf(b.x) > t) ? 0.0f : b.x;
    xs[rl][c8+5] = (fabsf(b.y) > t) ? 0.0f : b.y;
    xs[rl][c8+6] = (fabsf(b.z) > t) ? 0.0f : b.z;
    xs[rl][c8+7] = (fabsf(b.w) > t) ? 0.0f : b.w;
    const float4* q = (const float4*)(W + (size_t)kt*16 + tid*8);
    float4 wa = q[0], wb = q[1];
    float* dstw = &ws[wk][wc];
    dstw[0]=wa.x; dstw[1]=wa.y; dstw[2]=wa.z; dstw[3]=wa.w;
    dstw[4]=wb.x; dstw[5]=wb.y; dstw[6]=wb.z; dstw[7]=wb.w;
    __syncthreads();
    #pragma unroll
    for (int k=0;k<128;k+=2){
      float2 xv2 = *(const float2*)&xs[rl][k];
      acc += (double)xv2.x*(double)ws[k][c];
      acc += (double)xv2.y*(double)ws[k+1][c];
    }
    __syncthreads();
  }
  Y[(size_t)(row0+rl)*16 + c] = (float)acc;
}

__global__ __launch_bounds__(256) void k_gemmAT(const float* __restrict__ x, const float* __restrict__ Q,
                                                double* __restrict__ part, const float* __restrict__ sel){
  __shared__ float qs[128][16];
  const float t = sel[0];
  const int tid = threadIdx.x;
  const int d = blockIdx.x*256 + tid;
  const int chunk = blockIdx.y;
  const int i0 = chunk*(NROWS/NCHUNK);
  double acc[16];
  #pragma unroll
  for (int c=0;c<16;++c) acc[c]=0.0;
  for (int it=0; it<NROWS/NCHUNK; it+=128){
    if (tid < 128){
      const float4* src = (const float4*)(Q + (size_t)(i0+it+tid)*16);
      float4 a = src[0], b = src[1], c4 = src[2], d4 = src[3];
      float* dst = &qs[tid][0];
      dst[0]=a.x; dst[1]=a.y; dst[2]=a.z; dst[3]=a.w;
      dst[4]=b.x; dst[5]=b.y; dst[6]=b.z; dst[7]=b.w;
      dst[8]=c4.x; dst[9]=c4.y; dst[10]=c4.z; dst[11]=c4.w;
      dst[12]=d4.x; dst[13]=d4.y; dst[14]=d4.z; dst[15]=d4.w;
    }
    __syncthreads();
    for (int ii=0; ii<128; ++ii){
      float xv = x[(size_t)(i0+it+ii)*DDIM + d];
      xv = (fabsf(xv) > t) ? 0.0f : xv;
      double xd = (double)xv;
      #pragma unroll
      for (int c2=0;c2<8;++c2){
        float2 q2 = *(const float2*)&qs[ii][c2*2];
        acc[c2*2]   += xd*(double)q2.x;
        acc[c2*2+1] += xd*(double)q2.y;
      }
    }
    __syncthreads();
  }
  double* pp = part + ((size_t)chunk*DDIM + d)*16;
  #pragma unroll
  for (int c=0;c<16;++c) pp[c]=acc[c];
}

__global__ void k_reduceT(const double* __restrict__ part, float* __restrict__ outM, int asB, int nchunks){
  int idx = blockIdx.x*blockDim.x + threadIdx.x;
  if (idx >= DDIM*16) return;
  double s = 0.0;
  for (int c=0;c<nchunks;++c) s += part[(size_t)c*DDIM*16 + idx];
  int d = idx >> 4, r = idx & 15;
  if (asB) outM[(size_t)r*DDIM + d] = (float)s;
  else     outM[idx] = (float)s;
}

// ---------------- CholeskyQR building blocks ----------------
__device__ void redchol_body(const double* part, int nchunks, double* Lout, double* Uinv,
                             double (*Gs)[17], double (*Vs)[17], int t){
  {
    double s = 0.0;
    for (int c=0;c<nchunks;++c) s += part[(size_t)c*256 + t];
    Gs[t>>4][t&15] = s;
  }
  __syncthreads();
  int l = t;
  for (int k=0;k<16;++k){
    if (l==k) Gs[k][k] = fsqrt(Gs[k][k]);
    __syncthreads();
    if (l>k && l<16) Gs[k][l] = Gs[k][l]*frcp(Gs[k][k]);
    __syncthreads();
    if (l>k && l<16){
      double g = Gs[k][l];
      for (int i=k+1;i<=l;++i) Gs[i][l] -= Gs[k][i]*g;
    }
    __syncthreads();
  }
  if (l<16){
    for (int i=0;i<16;++i) Vs[i][l] = 0.0;
    Vs[l][l] = frcp(Gs[l][l]);
    for (int i=l-1;i>=0;--i){
      double s = 0.0;
      for (int k=i+1;k<=l;++k) s += Gs[i][k]*Vs[k][l];
      Vs[i][l] = -s*frcp(Gs[i][i]);
    }
  }
  __syncthreads();
  if (l<16){
    for (int c=0;c<16;++c){
      Lout[l*16+c] = (c<=l) ? Gs[c][l] : 0.0;
      Uinv[l*16+c] = (l<=c) ? Vs[l][c] : 0.0;
    }
  }
}

__global__ __launch_bounds__(256) void k_gramMC(const float* __restrict__ M, int rowsPerChunk,
                                                double* __restrict__ part,
                                                double* __restrict__ Lout, double* __restrict__ Uinv,
                                                unsigned* __restrict__ ctr){
  __shared__ float lds[16][17];
  __shared__ double Gs[16][17];
  __shared__ double Vs[16][17];
  __shared__ unsigned slast;
  int t = threadIdx.x; int i = t>>4, j = t&15;
  int r0 = blockIdx.x*rowsPerChunk;
  double acc = 0.0;
  for (int rt=0; rt<rowsPerChunk; rt+=16){
    lds[t>>4][t&15] = M[(size_t)(r0+rt+(t>>4))*16 + (t&15)];
    __syncthreads();
    #pragma unroll
    for (int dd2=0; dd2<16; ++dd2) acc += (double)lds[dd2][i]*(double)lds[dd2][j];
    __syncthreads();
  }
  part[(size_t)blockIdx.x*256 + t] = acc;
  __threadfence();
  if (t==0) slast = atomicAdd(ctr, 1u);
  __syncthreads();
  if (slast != gridDim.x-1u) return;
  __threadfence();
  redchol_body(part, (int)gridDim.x, Lout, Uinv, Gs, Vs, t);
  __syncthreads();
  if (t==0) *ctr = 0u;
}

__global__ __launch_bounds__(256) void k_gramBC(const float* __restrict__ B,
                                                double* __restrict__ part,
                                                double* __restrict__ Lout, double* __restrict__ Uinv,
                                                unsigned* __restrict__ ctr){
  __shared__ float lds[16][17];
  __shared__ double Gs[16][17];
  __shared__ double Vs[16][17];
  __shared__ unsigned slast;
  int t = threadIdx.x; int i = t>>4, j = t&15;
  int d0 = blockIdx.x*256;
  double acc = 0.0;
  for (int dt=0; dt<256; dt+=16){
    lds[t>>4][t&15] = B[(size_t)(t>>4)*DDIM + d0+dt+(t&15)];
    __syncthreads();
    #pragma unroll
    for (int dd2=0; dd2<16; ++dd2) acc += (double)lds[i][dd2]*(double)lds[j][dd2];
    __syncthreads();
  }
  part[(size_t)blockIdx.x*256 + t] = acc;
  __threadfence();
  if (t==0) slast = atomicAdd(ctr, 1u);
  __syncthreads();
  if (slast != gridDim.x-1u) return;
  __threadfence();
  redchol_body(part, (int)gridDim.x, Lout, Uinv, Gs, Vs, t);
  __syncthreads();
  if (t==0) *ctr = 0u;
}

__global__ __launch_bounds__(256) void k_applyRinv(float* __restrict__ M, const double* __restrict__ Uinv){
  __shared__ double su[256];
  int t = threadIdx.x;
  su[t] = Uinv[t];
  int r = blockIdx.x*16 + (t>>4);
  int j = t & 15;
  const float4* rp = (const float4*)(M + (size_t)r*16);
  float4 v0=rp[0], v1=rp[1], v2=rp[2], v3=rp[3];
  float rowv[16] = {v0.x,v0.y,v0.z,v0.w, v1.x,v1.y,v1.z,v1.w,
                    v2.x,v2.y,v2.z,v2.w, v3.x,v3.y,v3.z,v3.w};
  __syncthreads();
  double acc = 0.0;
  #pragma unroll
  for (int k=0;k<16;++k) acc += (double)rowv[k]*su[k*16+j];
  M[(size_t)r*16 + j] = (float)acc;
}

// ---------------- small SVD core (R8/R11 structure) ----------------
__global__ __launch_bounds__(64) void k_smallsvd(const double* __restrict__ Lg, double* __restrict__ Wout){
  __shared__ double Lm[16][16];
  __shared__ double VT[16][16];
  __shared__ double A1[16][16];
  __shared__ double dd[16], ee[16], tp[16];
  __shared__ double csv[16], snv[16];
  int l = threadIdx.x;
  for (int idx=l; idx<256; idx+=64){ int r=idx>>4, c=idx&15; Lm[r][c] = (c<=r)? Lg[r*16+c] : 0.0; }
  __syncthreads();
  for (int i=0;i<16;++i){
    double xn2=0.0;
    for (int r=i+1;r<16;++r){ double v=Lm[r][i]; xn2 += v*v; }
    double alpha = Lm[i][i];
    double beta, tauq_, scl;
    if (xn2==0.0){ tauq_=0.0; beta=alpha; scl=0.0; }
    else { beta = -dsign(fsqrt1(alpha*alpha+xn2), alpha); tauq_=(beta-alpha)*frcp1(beta); scl=frcp1(alpha-beta); }
    __syncthreads();
    if (l>i && l<16) Lm[l][i] *= scl;
    __syncthreads();
    dd[i]=beta;
    if (tauq_ != 0.0 && l>i && l<16){
      int j=l;
      double w = Lm[i][j];
      for (int r=i+1;r<16;++r) w += Lm[r][i]*Lm[r][j];
      w *= tauq_;
      Lm[i][j] -= w;
      for (int r=i+1;r<16;++r) Lm[r][j] -= w*Lm[r][i];
    }
    __syncthreads();
    if (i<15){
      double xn2b=0.0;
      for (int c=i+2;c<16;++c){ double v=Lm[i][c]; xn2b+=v*v; }
      double alpha2=Lm[i][i+1];
      double beta2, taup_, scl2;
      if (xn2b==0.0){ taup_=0.0; beta2=alpha2; scl2=0.0; }
      else { beta2=-dsign(fsqrt1(alpha2*alpha2+xn2b),alpha2); taup_=(beta2-alpha2)*frcp1(beta2); scl2=frcp1(alpha2-beta2); }
      __syncthreads();
      if (l>=i+2 && l<16) Lm[i][l] *= scl2;
      __syncthreads();
      ee[i]=beta2; tp[i]=taup_;
      if (taup_!=0.0 && l>i && l<16){
        int r=l;
        double w=Lm[r][i+1];
        for (int c=i+2;c<16;++c) w += Lm[i][c]*Lm[r][c];
        w *= taup_;
        Lm[r][i+1] -= w;
        for (int c=i+2;c<16;++c) Lm[r][c] -= w*Lm[i][c];
      }
      __syncthreads();
    } else { tp[i]=0.0; __syncthreads(); }
  }
  for (int idx=l; idx<256; idx+=64){ int r=idx>>4,c=idx&15; VT[r][c]=(r==c)?1.0:0.0; }
  __syncthreads();
  const double EPSs = 5.9604645e-8;
  const double UNFL = 1.17549435e-38;
  double tol = 10.0*EPSs;
  double sminoa, mu;
  sminoa = mu = fabs(dd[0]);
  if (sminoa != 0.0){
    for (int k=1;k<16;++k){ mu = fabs(dd[k])*(mu*frcp1(mu+fabs(ee[k-1]))); sminoa=fmin(sminoa,mu); if (sminoa==0.0) break; }
  }
  sminoa = sminoa/4.0;
  double thresh = fmax(tol*sminoa, 6.0*16.0*16.0*UNFL);
  int m=16, oldll=-1, oldm=-1, idir=0;
  double sminl=0.0;
  int guard=0;
  #define Dv(k) dd[(k)-1]
  #define Ev(k) ee[(k)-1]
  while (m > 1 && guard < 3000){
    ++guard;
    int ll=0; bool split=false;
    double smax_=fabs(Dv(m)), smin_=smax_;
    for (int lll=1; lll<=m-1; ++lll){
      ll = m-lll;
      double abss=fabs(Dv(ll)), abse=fabs(Ev(ll));
      if (abse <= thresh){ split=true; break; }
      smin_=fmin(smin_,abss); smax_=fmax(smax_,fmax(abss,abse));
    }
    if (!split) ll=0;
    else {
      Ev(ll)=0.0;
      if (ll == m-1){ m = m-1; continue; }
    }
    ll = ll+1;
    if (ll == m-1){
      double sigmn,sigmx,sinr,cosr,sinl_,cosl;
      f_slasv2(Dv(m-1), Ev(m-1), Dv(m), sigmn, sigmx, sinr, cosr, sinl_, cosl);
      Dv(m-1)=sigmx; Ev(m-1)=0.0; Dv(m)=sigmn;
      if (l<16){
        double t0 = cosr*VT[m-2][l] + sinr*VT[m-1][l];
        VT[m-1][l] = cosr*VT[m-1][l] - sinr*VT[m-2][l];
        VT[m-2][l] = t0;
      }
      __syncthreads();
      m -= 2; continue;
    }
    if (ll > oldm || m < oldll) idir = (fabs(Dv(ll)) >= fabs(Dv(m))) ? 1 : 2;
    bool cont=false;
    if (idir==1){
      if (fabs(Ev(m-1)) <= tol*fabs(Dv(m))){ Ev(m-1)=0.0; continue; }
      mu = fabs(Dv(ll)); sminl=mu;
      for (int lll=ll; lll<=m-1; ++lll){
        if (fabs(Ev(lll)) <= tol*mu){ Ev(lll)=0.0; cont=true; break; }
        mu = fabs(Dv(lll+1))*(mu*frcp1(mu+fabs(Ev(lll)))); sminl=fmin(sminl,mu);
      }
    } else {
      if (fabs(Ev(ll)) <= tol*fabs(Dv(ll))){ Ev(ll)=0.0; continue; }
      mu = fabs(Dv(m)); sminl=mu;
      for (int lll=m-1; lll>=ll; --lll){
        if (fabs(Ev(lll)) <= tol*mu){ Ev(lll)=0.0; cont=true; break; }
        mu = fabs(Dv(lll))*(mu*frcp1(mu+fabs(Ev(lll)))); sminl=fmin(sminl,mu);
      }
    }
    if (cont) continue;
    oldll=ll; oldm=m;
    double shift=0.0, rdum;
    if (!( 16.0*tol*(sminl*frcp1(smax_)) <= fmax(EPSs, 0.01*tol) )){
      double sll;
      if (idir==1){ sll=fabs(Dv(ll)); f_slas2(Dv(m-1), Ev(m-1), Dv(m), shift, rdum); }
      else        { sll=fabs(Dv(m));  f_slas2(Dv(ll), Ev(ll), Dv(ll+1), shift, rdum); }
      if (sll>0.0){ double q=shift*frcp1(sll); if (q*q < EPSs) shift=0.0; }
    }
    if (shift == 0.0){
      if (idir==1){
        double cs=1.0, oldcs=1.0, oldsn=0.0, r_;
        double dcur = Dv(ll);
        for (int i1=ll;i1<=m-1;++i1){
          double cn, snn;
          double a0 = dcur*cs;
          f_slartg(a0, Ev(i1), cn, snn, r_);
          if (i1>ll) Ev(i1-1) = oldsn*r_;
          double dnx = Dv(i1+1);
          double ocn, osn, dnew;
          f_slartg(oldcs*r_, dnx*snn, ocn, osn, dnew);
          Dv(i1)=dnew;
          cs=cn; oldcs=ocn; oldsn=osn;
          csv[i1-1]=cs; snv[i1-1]=snn;
          dcur = dnx;
        }
        double h=dcur*cs;
        Dv(m)=h*oldcs; Ev(m-1)=h*oldsn;
        if (fabs(Ev(m-1))<=thresh) Ev(m-1)=0.0;
        __syncthreads();
        if (l<16){
          double v = VT[ll-1][l];
          for (int i1=ll;i1<=m-1;++i1){
            double c=csv[i1-1], s=snv[i1-1];
            double w = VT[i1][l];
            VT[i1-1][l] = c*v + s*w;
            v = c*w - s*v;
          }
          VT[m-1][l] = v;
        }
      } else {
        double cs=1.0, oldcs=1.0, oldsn=0.0, r_;
        double dcur = Dv(m);
        for (int i1=m;i1>=ll+1;--i1){
          double cn,snn;
          double a0 = dcur*cs;
          f_slartg(a0, Ev(i1-1), cn, snn, r_);
          if (i1<m) Ev(i1)=oldsn*r_;
          double dnx = Dv(i1-1);
          double ocn,osn,dnew;
          f_slartg(oldcs*r_, dnx*snn, ocn, osn, dnew);
          Dv(i1)=dnew;
          cs=cn; oldcs=ocn; oldsn=osn;
          csv[i1-2]=oldcs; snv[i1-2]=-oldsn;
          dcur = dnx;
        }
        double h=dcur*cs;
        Dv(ll)=h*oldcs; Ev(ll)=h*oldsn;
        if (fabs(Ev(ll))<=thresh) Ev(ll)=0.0;
        __syncthreads();
        if (l<16){
          double v = VT[m-1][l];
          for (int i1=m;i1>=ll+1;--i1){
            double c=csv[i1-2], s=snv[i1-2];
            double w = VT[i1-2][l];
            VT[i1-1][l] = c*v - s*w;
            v = c*w + s*v;
          }
          VT[ll-1][l] = v;
        }
      }
    } else {
      if (idir==1){
        double f=(fabs(Dv(ll))-shift)*(dsign(1.0,Dv(ll))+shift*frcp1(Dv(ll)));
        double g=Ev(ll);
        double dcur = Dv(ll), ecur = Ev(ll);
        double r_;
        for (int i1=ll;i1<=m-1;++i1){
          double cosr,sinr,cosl,sinl_;
          double dnx = Dv(i1+1);
          f_slartg(f,g,cosr,sinr,r_);
          if (i1>ll) Ev(i1-1)=r_;
          f = cosr*dcur + sinr*ecur;
          double e_mid = cosr*ecur - sinr*dcur;
          g = sinr*dnx;
          double d_mid = cosr*dnx;
          f_slartg(f,g,cosl,sinl_,r_);
          Dv(i1)=r_;
          f = cosl*e_mid + sinl_*d_mid;
          double d_fin = cosl*d_mid - sinl_*e_mid;
          double e_fin = 0.0;
          if (i1 < m-1){ double enx = Ev(i1+1); g = sinl_*enx; e_fin = cosl*enx; }
          csv[i1-1]=cosr; snv[i1-1]=sinr;
          dcur = d_fin; ecur = e_fin;
        }
        Dv(m) = dcur;
        Ev(m-1)=f;
        if (fabs(Ev(m-1))<=thresh) Ev(m-1)=0.0;
        __syncthreads();
        if (l<16){
          double v = VT[ll-1][l];
          for (int i1=ll;i1<=m-1;++i1){
            double c=csv[i1-1], s=snv[i1-1];
            double w = VT[i1][l];
            VT[i1-1][l] = c*v + s*w;
            v = c*w - s*v;
          }
          VT[m-1][l] = v;
        }
      } else {
        double f=(fabs(Dv(m))-shift)*(dsign(1.0,Dv(m))+shift*frcp1(Dv(m)));
        double g=Ev(m-1);
        double dcur = Dv(m), ecur = Ev(m-1);
        double r_;
        for (int i1=m;i1>=ll+1;--i1){
          double cosr,sinr,cosl,sinl_;
          double dnx = Dv(i1-1);
          f_slartg(f,g,cosr,sinr,r_);
          if (i1<m) Ev(i1)=r_;
          f = cosr*dcur + sinr*ecur;
          double e_mid = cosr*ecur - sinr*dcur;
          g = sinr*dnx;
          double d_mid = cosr*dnx;
          f_slartg(f,g,cosl,sinl_,r_);
          Dv(i1)=r_;
          f = cosl*e_mid + sinl_*d_mid;
          double d_fin = cosl*d_mid - sinl_*e_mid;
          double e_fin = 0.0;
          if (i1 > ll+1){ double enx = Ev(i1-2); g = sinl_*enx; e_fin = cosl*enx; }
          csv[i1-2]=cosr; snv[i1-2]=-sinr;
          dcur = d_fin; ecur = e_fin;
        }
        Dv(ll) = dcur;
        Ev(ll)=f;
        if (fabs(Ev(ll))<=thresh) Ev(ll)=0.0;
        __syncthreads();
        if (l<16){
          double v = VT[m-1][l];
          for (int i1=m;i1>=ll+1;--i1){
            double c=csv[i1-2], s=snv[i1-2];
            double w = VT[i1-2][l];
            VT[i1-1][l] = c*v - s*w;
            v = c*w + s*v;
          }
          VT[ll-1][l] = v;
        }
      }
    }
    __syncthreads();
  }
  __syncthreads();
  for (int k=1;k<=16;++k){
    if (Dv(k) < 0.0){
      Dv(k) = -Dv(k);
      if (l<16) VT[k-1][l] = -VT[k-1][l];
    }
    __syncthreads();
  }
  for (int i1=1;i1<=15;++i1){
    int isub=1; double smn=Dv(1);
    for (int j=2;j<=17-i1;++j){ if (Dv(j) <= smn){ isub=j; smn=Dv(j);} }
    if (isub != 17-i1){
      double tmpd = Dv(17-i1);
      __syncthreads();
      Dv(isub)=tmpd; Dv(17-i1)=smn;
      if (l<16){ double t2=VT[isub-1][l]; VT[isub-1][l]=VT[16-i1][l]; VT[16-i1][l]=t2; }
    }
    __syncthreads();
  }
  for (int i=14;i>=0;--i){
    double tpv = tp[i];
    if (tpv != 0.0 && l<16){
      int r=l;
      double w = VT[r][i+1];
      for (int c=i+2;c<16;++c) w += VT[r][c]*Lm[i][c];
      w *= tpv;
      VT[r][i+1] -= w;
      for (int c=i+2;c<16;++c) VT[r][c] -= w*Lm[i][c];
    }
    __syncthreads();
  }
  if (l<16){
    int r=l;
    for (int j=15;j>=0;--j){
      double s = VT[r][j];
      for (int k=j+1;k<16;++k) s -= A1[r][k]*Lg[k*16+j];
      A1[r][j] = s*frcp1(Lg[j*16+j]);
    }
    for (int j=0;j<16;++j) Wout[r*16+j] = A1[r][j];
  }
  #undef Dv
  #undef Ev
}

// Vh = W @ B ; write R (4096x16) and Rinv (16x4096)
__global__ __launch_bounds__(256) void k_formVh2(const float* __restrict__ B, const double* __restrict__ W,
                                                 float* __restrict__ outR, float* __restrict__ outRinv){
  __shared__ double sW[256];
  int t = threadIdx.x;
  sW[t] = W[t];
  __syncthreads();
  int d = blockIdx.x*256 + t;
  double bi[16];
  #pragma unroll
  for (int i=0;i<16;++i) bi[i] = (double)B[(size_t)i*DDIM + d];
  #pragma unroll
  for (int r=0;r<16;++r){
    double s = 0.0;
    #pragma unroll
    for (int i=0;i<16;++i) s += sW[r*16+i]*bi[i];
    float f = (float)s;
    outRinv[(size_t)r*DDIM + d] = f;
    outR[(size_t)d*16 + r] = f;
  }
}

// ---------------- silu (fallback: last, frees scratch region) ----------------
__global__ void k_silu(const float4* __restrict__ x4, float4* __restrict__ o4){
  int tid = blockIdx.x*blockDim.x + threadIdx.x;
  int stride = gridDim.x*blockDim.x;
  for (int i = tid; i < N_TOTAL/4; i += stride){
    float4 v = x4[i];
    float4 o;
    o.x = v.x / (1.0f + expf(-v.x));
    o.y = v.y / (1.0f + expf(-v.y));
    o.z = v.z / (1.0f + expf(-v.z));
    o.w = v.w / (1.0f + expf(-v.w));
    o4[i] = o;
  }
}

// ---------------- launch ----------------
static void cholQR(float* M, int N, double* partG, double* Ld, double* Uinvd, unsigned* ctr,
                   hipStream_t stream){
  k_gramMC<<<32,256,0,stream>>>(M, N/32, partG, Ld, Uinvd, ctr);
  k_applyRinv<<<N/16,256,0,stream>>>(M, Uinvd);
}

extern "C" void kernel_launch(void* const* d_in, const int* in_sizes, int n_in,
                              void* d_out, int out_size, void* d_ws, size_t ws_size,
                              hipStream_t stream) {
  (void)in_sizes; (void)n_in; (void)out_size;
  const float* x = (const float*)d_in[0];
  float* out = (float*)d_out;
  const size_t NEEDED = 20512832;  // bytes of scratch (ends at partG end)
  const bool useWs = (d_ws != nullptr) && (ws_size >= NEEDED);
  float* scr = useWs ? (float*)d_ws : out;
  // scratch layout (float offsets from scr)
  unsigned* h1   = (unsigned*)scr;                 // [0, 4096)
  unsigned* h2   = (unsigned*)(scr + 4096);        // [4096, 528384)
  unsigned* ctr  = (unsigned*)(scr + 528384);      // counters (memset'd)
  unsigned* selu = (unsigned*)(scr + 528400);
  float*    self = (float*)selu;
  unsigned* gs   = (unsigned*)(scr + 528496);      // 1024 group sums
  float* Om = scr + 532496;                        // 65536
  float* Y  = scr + 598032;                        // 131072
  float* T  = scr + 729104;                        // 65536
  float* B  = scr + 794640;                        // 65536
  double* dsm  = (double*)(scr + 860192);          // f64 area (byte ofs %8==0)
  double* Ld   = dsm;
  double* Uinvd= dsm + 256;
  double* Wd   = dsm + 512;
  double* part = (double*)(scr + 917520);          // 32*65536 doubles = 16 MB
  double* partG= (double*)(scr + 5111824);         // 32*256 doubles
  float* outScalar = out + (size_t)N_TOTAL;
  float* outR      = out + (size_t)N_TOTAL + 1;
  float* outRinv   = out + (size_t)N_TOTAL + 1 + 65536;

  hipMemsetAsync(h1, 0, (4096+524288+16)*sizeof(unsigned), stream);
  if (useWs){
    k_siluhist<<<2048,256,0,stream>>>((const float4*)x, (float4*)out, h1);
  } else {
    k_hist1<<<1024,256,0,stream>>>((const float4*)x, h1);
  }
  k_select1<<<1,1024,0,stream>>>(h1, selu);
  k_hist2<<<2048,256,0,stream>>>((const float4*)x, h2, selu);
  k_grpsum<<<1024,128,0,stream>>>((const uint4*)h2, gs);
  k_select2b<<<1,1024,0,stream>>>(gs, h2, selu, outScalar);
  k_omega<<<128,256,0,stream>>>(Om);

  // Q = qr(Xs @ Omega)
  k_gemmA<<<512,256,0,stream>>>(x, Om, Y, self);
  cholQR(Y, NROWS, partG, Ld, Uinvd, ctr, stream);
  // 2 power iterations: Q = qr(Xs^T Q); Q = qr(Xs Q)
  for (int it=0; it<2; ++it){
    k_gemmAT<<<dim3(16,NCHUNK),256,0,stream>>>(x, Y, part, self);
    k_reduceT<<<256,256,0,stream>>>(part, T, 0, NCHUNK);
    cholQR(T, DDIM, partG, Ld, Uinvd, ctr, stream);
    k_gemmA<<<512,256,0,stream>>>(x, T, Y, self);
    cholQR(Y, NROWS, partG, Ld, Uinvd, ctr, stream);
  }
  // B = Q^T Xs  (16 x 4096)
  k_gemmAT<<<dim3(16,NCHUNK),256,0,stream>>>(x, Y, part, self);
  k_reduceT<<<256,256,0,stream>>>(part, B, 1, NCHUNK);
  // SVD path: G_B = B B^T -> L = chol -> gebd2+bdsqr on L -> W = VT L^-1 -> Vh = W B
  k_gramBC<<<16,256,0,stream>>>(B, partG, Ld, Uinvd, ctr);
  k_smallsvd<<<1,64,0,stream>>>(Ld, Wd);
  k_formVh2<<<16,256,0,stream>>>(B, Wd, outR, outRinv);
  if (!useWs){
    k_silu<<<2048,256,0,stream>>>((const float4*)x, (float4*)out);
  }
}